// Round 2
// baseline (1138.734 us; speedup 1.0000x reference)
//
#include <hip/hip_runtime.h>
#include <hip/hip_bf16.h>

#define N_NODES 200000
#define N_EDGES 800000
#define N_GRAPHS 4000
#define D_N 35
#define IN_CH 8
#define EMB 256
#define HID 128

typedef unsigned short u16;

__device__ __forceinline__ float b2f(u16 u) {
    union { float f; unsigned v; } x; x.v = ((unsigned)u) << 16; return x.f;
}
__device__ __forceinline__ u16 f2b(float f) {
    union { float f; unsigned v; } x; x.f = f;
    unsigned r = x.v + 0x7fff + ((x.v >> 16) & 1);  // round-nearest-even
    return (u16)(r >> 16);
}

// ---------------- CSR build ----------------

__global__ void count_deg(const int* __restrict__ dst, int* __restrict__ deg, int n) {
    int e = blockIdx.x * 256 + threadIdx.x;
    if (e < n) atomicAdd(&deg[dst[e]], 1);
}

// block = 256 threads, 1024 elems/block; writes inclusive scan into incl1 (= rowptr+1)
__global__ __launch_bounds__(256) void scan_a(const int* __restrict__ deg, int* __restrict__ incl1,
                                              int* __restrict__ partials, int n) {
    __shared__ int s[256];
    int tid = threadIdx.x;
    int base = blockIdx.x * 1024;
    int v[4]; int sum = 0;
#pragma unroll
    for (int j = 0; j < 4; j++) {
        int idx = base + tid * 4 + j;
        v[j] = (idx < n) ? deg[idx] : 0;
        sum += v[j];
    }
    s[tid] = sum; __syncthreads();
    for (int off = 1; off < 256; off <<= 1) {
        int t = (tid >= off) ? s[tid - off] : 0;
        __syncthreads();
        s[tid] += t;
        __syncthreads();
    }
    int run = s[tid] - sum;  // exclusive prefix of this thread
#pragma unroll
    for (int j = 0; j < 4; j++) {
        int idx = base + tid * 4 + j;
        run += v[j];
        if (idx < n) incl1[idx] = run;
    }
    if (tid == 255) partials[blockIdx.x] = s[255];
}

__global__ __launch_bounds__(256) void scan_b(int* __restrict__ partials, int np) {
    __shared__ int s[256];
    int tid = threadIdx.x;
    int v = (tid < np) ? partials[tid] : 0;
    s[tid] = v; __syncthreads();
    for (int off = 1; off < 256; off <<= 1) {
        int t = (tid >= off) ? s[tid - off] : 0;
        __syncthreads();
        s[tid] += t;
        __syncthreads();
    }
    if (tid < np) partials[tid] = s[tid] - v;  // exclusive
}

__global__ void scan_c(int* __restrict__ rowptr, const int* __restrict__ partials, int n) {
    int i = blockIdx.x * 256 + threadIdx.x;
    if (i < n) rowptr[1 + i] += partials[i >> 10];
    if (i == 0) rowptr[0] = 0;
}

__global__ void fill_csr(const int* __restrict__ src, const int* __restrict__ dst,
                         const int* __restrict__ rowptr, int* __restrict__ cursor,
                         int* __restrict__ csr, int n) {
    int e = blockIdx.x * 256 + threadIdx.x;
    if (e >= n) return;
    int d = dst[e];
    int p = atomicAdd(&cursor[d], 1);
    csr[rowptr[d] + p] = src[e];
}

// ---------------- feature pipeline ----------------

// h0 = x @ W_emb.T   [N,8]  (fp32)
__global__ __launch_bounds__(256) void emb_kernel(const float* __restrict__ x, const float* __restrict__ We,
                                                  float* __restrict__ h0, int n) {
    __shared__ float ws[IN_CH * D_N];
    int tid = threadIdx.x;
    for (int i = tid; i < IN_CH * D_N; i += 256) ws[i] = We[i];   // 280 > 256: strided fix
    __syncthreads();
    int node = blockIdx.x * 256 + tid;
    if (node >= n) return;
    float xr[D_N];
    const float* xp = &x[(size_t)node * D_N];
#pragma unroll
    for (int k = 0; k < D_N; k++) xr[k] = xp[k];
#pragma unroll
    for (int j = 0; j < IN_CH; j++) {
        float acc = 0.f;
#pragma unroll
        for (int k = 0; k < D_N; k++) acc += xr[k] * ws[j * D_N + k];
        h0[(size_t)node * IN_CH + j] = acc;
    }
}

// m8[n] = sum over in-edges of h0[src]   (8 lanes per node, fp32)
__global__ __launch_bounds__(256) void agg8(const float* __restrict__ h0, const int* __restrict__ rowptr,
                                            const int* __restrict__ csr, float* __restrict__ m8) {
    int tid = threadIdx.x;
    int n = blockIdx.x * 32 + (tid >> 3);
    int c = tid & 7;
    int s0 = rowptr[n], s1 = rowptr[n + 1];
    float acc = 0.f;
    for (int e = s0; e < s1; e++) {
        int s = csr[e];
        acc += h0[(size_t)s * IN_CH + c];
    }
    m8[(size_t)n * IN_CH + c] = acc;
}

// out = relu(m8 @ W1.T + b1)  [N,256] bf16; block = 16 nodes, thread = output channel
__global__ __launch_bounds__(256) void gemm1(const float* __restrict__ m8, const float* __restrict__ W1,
                                             const float* __restrict__ b1, u16* __restrict__ out) {
    __shared__ float ms[16][IN_CH];
    int n0 = blockIdx.x * 16;
    int tid = threadIdx.x;
    if (tid < 128) ms[tid >> 3][tid & 7] = m8[(size_t)(n0 + (tid >> 3)) * IN_CH + (tid & 7)];
    float w[IN_CH];
#pragma unroll
    for (int k = 0; k < IN_CH; k++) w[k] = W1[tid * IN_CH + k];
    float bo = b1[tid];
    __syncthreads();
#pragma unroll
    for (int i = 0; i < 16; i++) {
        float acc = bo;
#pragma unroll
        for (int k = 0; k < IN_CH; k++) acc += ms[i][k] * w[k];
        out[(size_t)(n0 + i) * EMB + tid] = f2b(fmaxf(acc, 0.f));
    }
}

// m[n,:] = sum over in-edges of h[src,:]  (one wave per node, 4 bf16 ch per lane, fp32 accum)
__global__ __launch_bounds__(256) void agg256(const u16* __restrict__ h, const int* __restrict__ rowptr,
                                              const int* __restrict__ csr, u16* __restrict__ m) {
    int wave = threadIdx.x >> 6;
    int lane = threadIdx.x & 63;
    int n = blockIdx.x * 4 + wave;
    int s0 = rowptr[n], s1 = rowptr[n + 1];
    float a0 = 0.f, a1 = 0.f, a2 = 0.f, a3 = 0.f;
    for (int e = s0; e < s1; e++) {
        int s = csr[e];
        ushort4 v = *(const ushort4*)&h[(size_t)s * EMB + lane * 4];
        a0 += b2f(v.x); a1 += b2f(v.y); a2 += b2f(v.z); a3 += b2f(v.w);
    }
    ushort4 o; o.x = f2b(a0); o.y = f2b(a1); o.z = f2b(a2); o.w = f2b(a3);
    *(ushort4*)&m[(size_t)n * EMB + lane * 4] = o;
}

__global__ void transpose256(const float* __restrict__ W, float* __restrict__ WT) {
    int k = blockIdx.x, o = threadIdx.x;
    WT[k * 256 + o] = W[o * 256 + k];
}

// H[64 rows x 256] = relu(Magg @ WT + bias) + H   (in-place on H; Magg read-only bf16)
__global__ __launch_bounds__(256) void gcn_gemm(const u16* __restrict__ Magg, const float* __restrict__ WT,
                                                const float* __restrict__ bias, u16* __restrict__ H) {
    __shared__ float As[16][68];    // [k][n]
    __shared__ float Bs[16][260];   // [k][o]
    const int row0 = blockIdx.x * 64;
    const int tid = threadIdx.x;
    const int tx = tid & 15, ty = tid >> 4;
    const int ldn = tid >> 2, ldk4 = (tid & 3) * 4;
    const int bk = tid >> 4, bo4 = (tid & 15) * 4;
    float acc[4][16];
#pragma unroll
    for (int i = 0; i < 4; i++)
#pragma unroll
        for (int j = 0; j < 16; j++) acc[i][j] = 0.f;

    for (int k0 = 0; k0 < 256; k0 += 16) {
        ushort4 a = *(const ushort4*)&Magg[(size_t)(row0 + ldn) * EMB + k0 + ldk4];
        float4 bq[4];
#pragma unroll
        for (int j = 0; j < 4; j++)
            bq[j] = *(const float4*)&WT[(size_t)(k0 + bk) * 256 + j * 64 + bo4];
        __syncthreads();
        As[ldk4 + 0][ldn] = b2f(a.x);
        As[ldk4 + 1][ldn] = b2f(a.y);
        As[ldk4 + 2][ldn] = b2f(a.z);
        As[ldk4 + 3][ldn] = b2f(a.w);
#pragma unroll
        for (int j = 0; j < 4; j++)
            *(float4*)&Bs[bk][j * 64 + bo4] = bq[j];
        __syncthreads();
#pragma unroll
        for (int k = 0; k < 16; k++) {
            float4 a4 = *(const float4*)&As[k][ty * 4];
            float av[4] = {a4.x, a4.y, a4.z, a4.w};
#pragma unroll
            for (int j4 = 0; j4 < 4; j4++) {
                float4 b4 = *(const float4*)&Bs[k][j4 * 64 + tx * 4];
                float bv[4] = {b4.x, b4.y, b4.z, b4.w};
#pragma unroll
                for (int i = 0; i < 4; i++)
#pragma unroll
                    for (int jj = 0; jj < 4; jj++)
                        acc[i][j4 * 4 + jj] += av[i] * bv[jj];
            }
        }
        __syncthreads();
    }
    // epilogue: H = relu(acc + bias) + H (read-then-write same location per thread)
#pragma unroll
    for (int i = 0; i < 4; i++) {
        int r = row0 + ty * 4 + i;
#pragma unroll
        for (int j4 = 0; j4 < 4; j4++) {
            int c = j4 * 64 + tx * 4;
            float4 bb = *(const float4*)&bias[c];
            ushort4 hh = *(const ushort4*)&H[(size_t)r * EMB + c];
            ushort4 o;
            o.x = f2b(fmaxf(acc[i][j4 * 4 + 0] + bb.x, 0.f) + b2f(hh.x));
            o.y = f2b(fmaxf(acc[i][j4 * 4 + 1] + bb.y, 0.f) + b2f(hh.y));
            o.z = f2b(fmaxf(acc[i][j4 * 4 + 2] + bb.z, 0.f) + b2f(hh.z));
            o.w = f2b(fmaxf(acc[i][j4 * 4 + 3] + bb.w, 0.f) + b2f(hh.w));
            *(ushort4*)&H[(size_t)r * EMB + c] = o;
        }
    }
}

// ---------------- pooling + head ----------------

__global__ void graph_bounds(const int* __restrict__ seg, int* __restrict__ gs, int n, int B) {
    int i = blockIdx.x * 256 + threadIdx.x;
    if (i >= n) return;
    int c = seg[i];
    int p = (i == 0) ? -1 : seg[i - 1];
    for (int b = p + 1; b <= c; b++) gs[b] = i;
    if (i == n - 1) {
        for (int b = c + 1; b <= B; b++) gs[b] = n;
    }
}

__global__ __launch_bounds__(256) void pool_kernel(const u16* __restrict__ h, const int* __restrict__ gs,
                                                   float* __restrict__ g) {
    int b = blockIdx.x, t = threadIdx.x;
    int s = gs[b], e = gs[b + 1];
    float acc = 0.f;
    for (int n = s; n < e; n++) acc += b2f(h[(size_t)n * EMB + t]);
    g[(size_t)b * EMB + t] = acc;
}

__global__ __launch_bounds__(128) void head_kernel(const float* __restrict__ g, const float* __restrict__ Wp1,
                                                   const float* __restrict__ Wp2, const float* __restrict__ bp2,
                                                   float* __restrict__ out) {
    __shared__ float gsm[EMB];
    __shared__ float red[HID];
    int b = blockIdx.x, t = threadIdx.x;
    gsm[t] = g[(size_t)b * EMB + t];
    gsm[t + 128] = g[(size_t)b * EMB + t + 128];
    __syncthreads();
    float acc = 0.f;
    const float* wr = &Wp1[(size_t)t * EMB];
#pragma unroll 4
    for (int k = 0; k < EMB; k++) acc += gsm[k] * wr[k];
    red[t] = fmaxf(acc, 0.f) * Wp2[t];
    __syncthreads();
    for (int off = 64; off > 0; off >>= 1) {
        if (t < off) red[t] += red[t + off];
        __syncthreads();
    }
    if (t == 0) out[b] = red[0] + bp2[0];
}

// ---------------- launch ----------------

extern "C" void kernel_launch(void* const* d_in, const int* in_sizes, int n_in,
                              void* d_out, int out_size, void* d_ws, size_t ws_size,
                              hipStream_t stream) {
    const float* x    = (const float*)d_in[0];
    const int*   src  = (const int*)d_in[1];
    const int*   dst  = (const int*)d_in[2];
    const int*   seg  = (const int*)d_in[3];
    const float* W_emb= (const float*)d_in[4];
    const float* W1   = (const float*)d_in[5];
    const float* b1   = (const float*)d_in[6];
    const float* W2   = (const float*)d_in[7];
    const float* b2   = (const float*)d_in[8];
    const float* W3   = (const float*)d_in[9];
    const float* b3   = (const float*)d_in[10];
    const float* Wp1  = (const float*)d_in[11];
    const float* Wp2  = (const float*)d_in[12];
    const float* bp2  = (const float*)d_in[13];
    float* out = (float*)d_out;

    char* ws = (char*)d_ws;
    size_t off = 0;
    auto alloc = [&](size_t bytes) -> void* {
        void* p = ws + off;
        off = (off + bytes + 255) & ~(size_t)255;
        return p;
    };
    const int N = N_NODES, E = N_EDGES, G = N_GRAPHS;
    float* h0   = (float*)alloc((size_t)N * IN_CH * 4);
    float* m8   = (float*)alloc((size_t)N * IN_CH * 4);
    u16* hA     = (u16*)alloc((size_t)N * EMB * 2);   // feature/residual buffer (bf16)
    u16* hB     = (u16*)alloc((size_t)N * EMB * 2);   // aggregation buffer (bf16)
    float* WT2  = (float*)alloc(256 * 256 * 4);
    float* WT3  = (float*)alloc(256 * 256 * 4);
    int* rowptr = (int*)alloc((size_t)(N + 1) * 4);
    int* deg    = (int*)alloc((size_t)N * 4);
    int* csr    = (int*)alloc((size_t)E * 4);
    int* partials = (int*)alloc(1024 * 4);
    int* gs     = (int*)alloc((size_t)(G + 1) * 4);
    float* g    = (float*)alloc((size_t)G * EMB * 4);

    // Workspace guard: if insufficient, launch nothing (clean validation failure,
    // distinguishes "ws too small" from a device fault).
    if (off > ws_size) return;

    // CSR build (by dst)
    hipMemsetAsync(deg, 0, (size_t)N * 4, stream);
    count_deg<<<E / 256, 256, 0, stream>>>(dst, deg, E);
    scan_a<<<196, 256, 0, stream>>>(deg, rowptr + 1, partials, N);
    scan_b<<<1, 256, 0, stream>>>(partials, 196);
    scan_c<<<782, 256, 0, stream>>>(rowptr, partials, N);
    hipMemsetAsync(deg, 0, (size_t)N * 4, stream);  // reuse as cursor
    fill_csr<<<E / 256, 256, 0, stream>>>(src, dst, rowptr, deg, csr, E);

    // features
    emb_kernel<<<782, 256, 0, stream>>>(x, W_emb, h0, N);
    agg8<<<N / 32, 256, 0, stream>>>(h0, rowptr, csr, m8);
    gemm1<<<N / 16, 256, 0, stream>>>(m8, W1, b1, hA);

    transpose256<<<256, 256, 0, stream>>>(W2, WT2);
    transpose256<<<256, 256, 0, stream>>>(W3, WT3);

    // layer 2: hA = relu(agg(hA) @ W2.T + b2) + hA
    agg256<<<N / 4, 256, 0, stream>>>(hA, rowptr, csr, hB);
    gcn_gemm<<<N / 64, 256, 0, stream>>>(hB, WT2, b2, hA);

    // layer 3: hA = relu(agg(hA) @ W3.T + b3) + hA
    agg256<<<N / 4, 256, 0, stream>>>(hA, rowptr, csr, hB);
    gcn_gemm<<<N / 64, 256, 0, stream>>>(hB, WT3, b3, hA);

    // pooling + head
    graph_bounds<<<782, 256, 0, stream>>>(seg, gs, N, G);
    pool_kernel<<<G, 256, 0, stream>>>(hA, gs, g);
    head_kernel<<<G, 128, 0, stream>>>(g, Wp1, Wp2, bp2, out);
}

// Round 3
// 706.149 us; speedup vs baseline: 1.6126x; 1.6126x over previous
//
#include <hip/hip_runtime.h>
#include <hip/hip_bf16.h>

#define N_NODES 200000
#define N_EDGES 800000
#define N_GRAPHS 4000
#define D_N 35
#define IN_CH 8
#define EMB 256
#define HID 128

typedef unsigned short u16;
typedef __attribute__((ext_vector_type(8))) short bf16x8;
typedef __attribute__((ext_vector_type(4))) float f32x4;

__device__ __forceinline__ float b2f(u16 u) {
    union { float f; unsigned v; } x; x.v = ((unsigned)u) << 16; return x.f;
}
__device__ __forceinline__ u16 f2b(float f) {
    union { float f; unsigned v; } x; x.f = f;
    unsigned r = x.v + 0x7fff + ((x.v >> 16) & 1);  // round-nearest-even
    return (u16)(r >> 16);
}

// ---------------- CSR build ----------------

__global__ void count_deg(const int* __restrict__ dst, int* __restrict__ deg, int n) {
    int e = blockIdx.x * 256 + threadIdx.x;
    if (e < n) atomicAdd(&deg[dst[e]], 1);
}

__global__ __launch_bounds__(256) void scan_a(const int* __restrict__ deg, int* __restrict__ incl1,
                                              int* __restrict__ partials, int n) {
    __shared__ int s[256];
    int tid = threadIdx.x;
    int base = blockIdx.x * 1024;
    int v[4]; int sum = 0;
#pragma unroll
    for (int j = 0; j < 4; j++) {
        int idx = base + tid * 4 + j;
        v[j] = (idx < n) ? deg[idx] : 0;
        sum += v[j];
    }
    s[tid] = sum; __syncthreads();
    for (int off = 1; off < 256; off <<= 1) {
        int t = (tid >= off) ? s[tid - off] : 0;
        __syncthreads();
        s[tid] += t;
        __syncthreads();
    }
    int run = s[tid] - sum;
#pragma unroll
    for (int j = 0; j < 4; j++) {
        int idx = base + tid * 4 + j;
        run += v[j];
        if (idx < n) incl1[idx] = run;
    }
    if (tid == 255) partials[blockIdx.x] = s[255];
}

__global__ __launch_bounds__(256) void scan_b(int* __restrict__ partials, int np) {
    __shared__ int s[256];
    int tid = threadIdx.x;
    int v = (tid < np) ? partials[tid] : 0;
    s[tid] = v; __syncthreads();
    for (int off = 1; off < 256; off <<= 1) {
        int t = (tid >= off) ? s[tid - off] : 0;
        __syncthreads();
        s[tid] += t;
        __syncthreads();
    }
    if (tid < np) partials[tid] = s[tid] - v;
}

__global__ void scan_c(int* __restrict__ rowptr, const int* __restrict__ partials, int n) {
    int i = blockIdx.x * 256 + threadIdx.x;
    if (i < n) rowptr[1 + i] += partials[i >> 10];
    if (i == 0) rowptr[0] = 0;
}

__global__ void fill_csr(const int* __restrict__ src, const int* __restrict__ dst,
                         const int* __restrict__ rowptr, int* __restrict__ cursor,
                         int* __restrict__ csr, int n) {
    int e = blockIdx.x * 256 + threadIdx.x;
    if (e >= n) return;
    int d = dst[e];
    int p = atomicAdd(&cursor[d], 1);
    csr[rowptr[d] + p] = src[e];
}

// ---------------- feature pipeline ----------------

// h0 = x @ W_emb.T   [N,8]  (fp32)
__global__ __launch_bounds__(256) void emb_kernel(const float* __restrict__ x, const float* __restrict__ We,
                                                  float* __restrict__ h0, int n) {
    __shared__ float ws[IN_CH * D_N];
    int tid = threadIdx.x;
    for (int i = tid; i < IN_CH * D_N; i += 256) ws[i] = We[i];
    __syncthreads();
    int node = blockIdx.x * 256 + tid;
    if (node >= n) return;
    float xr[D_N];
    const float* xp = &x[(size_t)node * D_N];
#pragma unroll
    for (int k = 0; k < D_N; k++) xr[k] = xp[k];
#pragma unroll
    for (int j = 0; j < IN_CH; j++) {
        float acc = 0.f;
#pragma unroll
        for (int k = 0; k < D_N; k++) acc += xr[k] * ws[j * D_N + k];
        h0[(size_t)node * IN_CH + j] = acc;
    }
}

// m8[n] = sum over in-edges of h0[src]   (8 lanes per node, fp32)
__global__ __launch_bounds__(256) void agg8(const float* __restrict__ h0, const int* __restrict__ rowptr,
                                            const int* __restrict__ csr, float* __restrict__ m8) {
    int tid = threadIdx.x;
    int n = blockIdx.x * 32 + (tid >> 3);
    int c = tid & 7;
    int s0 = rowptr[n], s1 = rowptr[n + 1];
    float acc = 0.f;
    for (int e = s0; e < s1; e++) {
        int s = csr[e];
        acc += h0[(size_t)s * IN_CH + c];
    }
    m8[(size_t)n * IN_CH + c] = acc;
}

// out = relu(m8 @ W1.T + b1)  [N,256] bf16; block = 16 nodes, thread = output channel
__global__ __launch_bounds__(256) void gemm1(const float* __restrict__ m8, const float* __restrict__ W1,
                                             const float* __restrict__ b1, u16* __restrict__ out) {
    __shared__ float ms[16][IN_CH];
    int n0 = blockIdx.x * 16;
    int tid = threadIdx.x;
    if (tid < 128) ms[tid >> 3][tid & 7] = m8[(size_t)(n0 + (tid >> 3)) * IN_CH + (tid & 7)];
    float w[IN_CH];
#pragma unroll
    for (int k = 0; k < IN_CH; k++) w[k] = W1[tid * IN_CH + k];
    float bo = b1[tid];
    __syncthreads();
#pragma unroll
    for (int i = 0; i < 16; i++) {
        float acc = bo;
#pragma unroll
        for (int k = 0; k < IN_CH; k++) acc += ms[i][k] * w[k];
        out[(size_t)(n0 + i) * EMB + tid] = f2b(fmaxf(acc, 0.f));
    }
}

// m[n,:] = sum over in-edges of h[src,:]  (one wave per node, 4 bf16 ch per lane, fp32 accum)
__global__ __launch_bounds__(256) void agg256(const u16* __restrict__ h, const int* __restrict__ rowptr,
                                              const int* __restrict__ csr, u16* __restrict__ m) {
    int wave = threadIdx.x >> 6;
    int lane = threadIdx.x & 63;
    int n = blockIdx.x * 4 + wave;
    int s0 = rowptr[n], s1 = rowptr[n + 1];
    float a0 = 0.f, a1 = 0.f, a2 = 0.f, a3 = 0.f;
    for (int e = s0; e < s1; e++) {
        int s = csr[e];
        ushort4 v = *(const ushort4*)&h[(size_t)s * EMB + lane * 4];
        a0 += b2f(v.x); a1 += b2f(v.y); a2 += b2f(v.z); a3 += b2f(v.w);
    }
    ushort4 o; o.x = f2b(a0); o.y = f2b(a1); o.z = f2b(a2); o.w = f2b(a3);
    *(ushort4*)&m[(size_t)n * EMB + lane * 4] = o;
}

// Pack W [256 out][256 in] fp32 into MFMA B-fragment order, bf16:
// Wsw[((nt*8+ks)*64 + lane)*8 + j] = bf16( W[nt*16+(lane&15)][ks*32+(lane>>4)*8+j] )
__global__ __launch_bounds__(256) void swizzle_w(const float* __restrict__ W, u16* __restrict__ Wsw) {
    int t = blockIdx.x * 256 + threadIdx.x;  // 8192 threads
    int lane = t & 63;
    int n = ((t >> 9) << 4) + (lane & 15);        // nt*16 + (lane&15)
    int k0 = (((t >> 6) & 7) << 5) + ((lane >> 4) << 3);  // ks*32 + (lane>>4)*8
    u16 v[8];
#pragma unroll
    for (int j = 0; j < 8; j++) v[j] = f2b(W[(size_t)n * 256 + k0 + j]);
    ushort4* o = (ushort4*)&Wsw[(size_t)t * 8];
    o[0] = make_ushort4(v[0], v[1], v[2], v[3]);
    o[1] = make_ushort4(v[4], v[5], v[6], v[7]);
}

// H[row0..row0+63][0..255] = relu(Magg @ W.T + bias) + H   (in-place on H)
// 4 waves/block, wave owns 16 rows. A-frags direct from global; B-frags from pre-swizzled Wsw.
__global__ __launch_bounds__(256) void gcn_gemm_mfma(const u16* __restrict__ Magg,
                                                     const u16* __restrict__ Wsw,
                                                     const float* __restrict__ bias,
                                                     u16* __restrict__ H) {
    const int wid = threadIdx.x >> 6;
    const int lane = threadIdx.x & 63;
    const int row0 = blockIdx.x * 64 + wid * 16;
    const int m = lane & 15;
    const int g = lane >> 4;

    // preload full K=256 of this lane's A row: 8 fragments of 8 bf16
    bf16x8 a[8];
    const u16* arow = &Magg[(size_t)(row0 + m) * EMB + g * 8];
#pragma unroll
    for (int ks = 0; ks < 8; ks++)
        a[ks] = *(const bf16x8*)(arow + ks * 32);

    f32x4 acc[16];
#pragma unroll
    for (int nt = 0; nt < 16; nt++) acc[nt] = (f32x4){0.f, 0.f, 0.f, 0.f};

    const bf16x8* wp = (const bf16x8*)Wsw + lane;
#pragma unroll
    for (int nt = 0; nt < 16; nt++) {
        bf16x8 b[8];
#pragma unroll
        for (int ks = 0; ks < 8; ks++) b[ks] = wp[(nt * 8 + ks) * 64];
#pragma unroll
        for (int ks = 0; ks < 8; ks++)
            acc[nt] = __builtin_amdgcn_mfma_f32_16x16x32_bf16(a[ks], b[ks], acc[nt], 0, 0, 0);
    }

    // epilogue: C/D layout col = lane&15, row = (lane>>4)*4 + reg  [m89/m91]
#pragma unroll
    for (int nt = 0; nt < 16; nt++) {
        int c = nt * 16 + m;
        float bv = bias[c];
#pragma unroll
        for (int r = 0; r < 4; r++) {
            int rr = row0 + g * 4 + r;
            size_t idx = (size_t)rr * EMB + c;
            H[idx] = f2b(fmaxf(acc[nt][r] + bv, 0.f) + b2f(H[idx]));
        }
    }
}

// ---------------- pooling + head ----------------

__global__ void graph_bounds(const int* __restrict__ seg, int* __restrict__ gs, int n, int B) {
    int i = blockIdx.x * 256 + threadIdx.x;
    if (i >= n) return;
    int c = seg[i];
    int p = (i == 0) ? -1 : seg[i - 1];
    for (int b = p + 1; b <= c; b++) gs[b] = i;
    if (i == n - 1) {
        for (int b = c + 1; b <= B; b++) gs[b] = n;
    }
}

__global__ __launch_bounds__(256) void pool_kernel(const u16* __restrict__ h, const int* __restrict__ gs,
                                                   float* __restrict__ g) {
    int b = blockIdx.x, t = threadIdx.x;
    int s = gs[b], e = gs[b + 1];
    float acc = 0.f;
    for (int n = s; n < e; n++) acc += b2f(h[(size_t)n * EMB + t]);
    g[(size_t)b * EMB + t] = acc;
}

__global__ __launch_bounds__(128) void head_kernel(const float* __restrict__ g, const float* __restrict__ Wp1,
                                                   const float* __restrict__ Wp2, const float* __restrict__ bp2,
                                                   float* __restrict__ out) {
    __shared__ float gsm[EMB];
    __shared__ float red[HID];
    int b = blockIdx.x, t = threadIdx.x;
    gsm[t] = g[(size_t)b * EMB + t];
    gsm[t + 128] = g[(size_t)b * EMB + t + 128];
    __syncthreads();
    float acc = 0.f;
    const float* wr = &Wp1[(size_t)t * EMB];
#pragma unroll 4
    for (int k = 0; k < EMB; k++) acc += gsm[k] * wr[k];
    red[t] = fmaxf(acc, 0.f) * Wp2[t];
    __syncthreads();
    for (int off = 64; off > 0; off >>= 1) {
        if (t < off) red[t] += red[t + off];
        __syncthreads();
    }
    if (t == 0) out[b] = red[0] + bp2[0];
}

// ---------------- launch ----------------

extern "C" void kernel_launch(void* const* d_in, const int* in_sizes, int n_in,
                              void* d_out, int out_size, void* d_ws, size_t ws_size,
                              hipStream_t stream) {
    const float* x    = (const float*)d_in[0];
    const int*   src  = (const int*)d_in[1];
    const int*   dst  = (const int*)d_in[2];
    const int*   seg  = (const int*)d_in[3];
    const float* W_emb= (const float*)d_in[4];
    const float* W1   = (const float*)d_in[5];
    const float* b1   = (const float*)d_in[6];
    const float* W2   = (const float*)d_in[7];
    const float* b2   = (const float*)d_in[8];
    const float* W3   = (const float*)d_in[9];
    const float* b3   = (const float*)d_in[10];
    const float* Wp1  = (const float*)d_in[11];
    const float* Wp2  = (const float*)d_in[12];
    const float* bp2  = (const float*)d_in[13];
    float* out = (float*)d_out;

    char* ws = (char*)d_ws;
    size_t off = 0;
    auto alloc = [&](size_t bytes) -> void* {
        void* p = ws + off;
        off = (off + bytes + 255) & ~(size_t)255;
        return p;
    };
    const int N = N_NODES, E = N_EDGES, G = N_GRAPHS;
    float* h0   = (float*)alloc((size_t)N * IN_CH * 4);
    float* m8   = (float*)alloc((size_t)N * IN_CH * 4);
    u16* hA     = (u16*)alloc((size_t)N * EMB * 2);   // feature/residual buffer (bf16)
    u16* hB     = (u16*)alloc((size_t)N * EMB * 2);   // aggregation buffer (bf16)
    u16* Wsw2   = (u16*)alloc(256 * 256 * 2);
    u16* Wsw3   = (u16*)alloc(256 * 256 * 2);
    int* rowptr = (int*)alloc((size_t)(N + 1) * 4);
    int* deg    = (int*)alloc((size_t)N * 4);
    int* csr    = (int*)alloc((size_t)E * 4);
    int* partials = (int*)alloc(1024 * 4);
    int* gs     = (int*)alloc((size_t)(G + 1) * 4);
    float* g    = (float*)alloc((size_t)G * EMB * 4);

    if (off > ws_size) return;  // clean failure instead of OOB crash

    // CSR build (by dst)
    hipMemsetAsync(deg, 0, (size_t)N * 4, stream);
    count_deg<<<E / 256, 256, 0, stream>>>(dst, deg, E);
    scan_a<<<196, 256, 0, stream>>>(deg, rowptr + 1, partials, N);
    scan_b<<<1, 256, 0, stream>>>(partials, 196);
    scan_c<<<782, 256, 0, stream>>>(rowptr, partials, N);
    hipMemsetAsync(deg, 0, (size_t)N * 4, stream);  // reuse as cursor
    fill_csr<<<E / 256, 256, 0, stream>>>(src, dst, rowptr, deg, csr, E);

    // features
    emb_kernel<<<782, 256, 0, stream>>>(x, W_emb, h0, N);
    agg8<<<N / 32, 256, 0, stream>>>(h0, rowptr, csr, m8);
    gemm1<<<N / 16, 256, 0, stream>>>(m8, W1, b1, hA);

    swizzle_w<<<32, 256, 0, stream>>>(W2, Wsw2);
    swizzle_w<<<32, 256, 0, stream>>>(W3, Wsw3);

    // layer 2: hA = relu(agg(hA) @ W2.T + b2) + hA
    agg256<<<N / 4, 256, 0, stream>>>(hA, rowptr, csr, hB);
    gcn_gemm_mfma<<<N / 64, 256, 0, stream>>>(hB, Wsw2, b2, hA);

    // layer 3: hA = relu(agg(hA) @ W3.T + b3) + hA
    agg256<<<N / 4, 256, 0, stream>>>(hA, rowptr, csr, hB);
    gcn_gemm_mfma<<<N / 64, 256, 0, stream>>>(hB, Wsw3, b3, hA);

    // pooling + head
    graph_bounds<<<782, 256, 0, stream>>>(seg, gs, N, G);
    pool_kernel<<<G, 256, 0, stream>>>(hA, gs, g);
    head_kernel<<<G, 128, 0, stream>>>(g, Wp1, Wp2, bp2, out);
}

// Round 4
// 632.975 us; speedup vs baseline: 1.7990x; 1.1156x over previous
//
#include <hip/hip_runtime.h>
#include <hip/hip_bf16.h>

#define N_NODES 200000
#define N_EDGES 800000
#define N_GRAPHS 4000
#define D_N 35
#define IN_CH 8
#define EMB 256
#define HID 128

typedef unsigned short u16;
typedef __attribute__((ext_vector_type(8))) short bf16x8;
typedef __attribute__((ext_vector_type(8))) unsigned short ushort8;
typedef __attribute__((ext_vector_type(4))) float f32x4;

__device__ __forceinline__ float b2f(u16 u) {
    union { float f; unsigned v; } x; x.v = ((unsigned)u) << 16; return x.f;
}
__device__ __forceinline__ u16 f2b(float f) {
    union { float f; unsigned v; } x; x.f = f;
    unsigned r = x.v + 0x7fff + ((x.v >> 16) & 1);  // round-nearest-even
    return (u16)(r >> 16);
}

// ---------------- CSR build ----------------

__global__ void count_deg(const int* __restrict__ dst, int* __restrict__ deg, int n) {
    int e = blockIdx.x * 256 + threadIdx.x;
    if (e < n) atomicAdd(&deg[dst[e]], 1);
}

__global__ __launch_bounds__(256) void scan_a(const int* __restrict__ deg, int* __restrict__ incl1,
                                              int* __restrict__ partials, int n) {
    __shared__ int s[256];
    int tid = threadIdx.x;
    int base = blockIdx.x * 1024;
    int v[4]; int sum = 0;
#pragma unroll
    for (int j = 0; j < 4; j++) {
        int idx = base + tid * 4 + j;
        v[j] = (idx < n) ? deg[idx] : 0;
        sum += v[j];
    }
    s[tid] = sum; __syncthreads();
    for (int off = 1; off < 256; off <<= 1) {
        int t = (tid >= off) ? s[tid - off] : 0;
        __syncthreads();
        s[tid] += t;
        __syncthreads();
    }
    int run = s[tid] - sum;
#pragma unroll
    for (int j = 0; j < 4; j++) {
        int idx = base + tid * 4 + j;
        run += v[j];
        if (idx < n) incl1[idx] = run;
    }
    if (tid == 255) partials[blockIdx.x] = s[255];
}

__global__ __launch_bounds__(256) void scan_b(int* __restrict__ partials, int np) {
    __shared__ int s[256];
    int tid = threadIdx.x;
    int v = (tid < np) ? partials[tid] : 0;
    s[tid] = v; __syncthreads();
    for (int off = 1; off < 256; off <<= 1) {
        int t = (tid >= off) ? s[tid - off] : 0;
        __syncthreads();
        s[tid] += t;
        __syncthreads();
    }
    if (tid < np) partials[tid] = s[tid] - v;
}

__global__ void scan_c(int* __restrict__ rowptr, const int* __restrict__ partials, int n) {
    int i = blockIdx.x * 256 + threadIdx.x;
    if (i < n) rowptr[1 + i] += partials[i >> 10];
    if (i == 0) rowptr[0] = 0;
}

__global__ void fill_csr(const int* __restrict__ src, const int* __restrict__ dst,
                         const int* __restrict__ rowptr, int* __restrict__ cursor,
                         int* __restrict__ csr, int n) {
    int e = blockIdx.x * 256 + threadIdx.x;
    if (e >= n) return;
    int d = dst[e];
    int p = atomicAdd(&cursor[d], 1);
    csr[rowptr[d] + p] = src[e];
}

// ---------------- layer-1 feature pipeline ----------------

// h0 = x @ W_emb.T   [N,8]  (fp32)
__global__ __launch_bounds__(256) void emb_kernel(const float* __restrict__ x, const float* __restrict__ We,
                                                  float* __restrict__ h0, int n) {
    __shared__ float ws[IN_CH * D_N];
    int tid = threadIdx.x;
    for (int i = tid; i < IN_CH * D_N; i += 256) ws[i] = We[i];
    __syncthreads();
    int node = blockIdx.x * 256 + tid;
    if (node >= n) return;
    float xr[D_N];
    const float* xp = &x[(size_t)node * D_N];
#pragma unroll
    for (int k = 0; k < D_N; k++) xr[k] = xp[k];
#pragma unroll
    for (int j = 0; j < IN_CH; j++) {
        float acc = 0.f;
#pragma unroll
        for (int k = 0; k < D_N; k++) acc += xr[k] * ws[j * D_N + k];
        h0[(size_t)node * IN_CH + j] = acc;
    }
}

// m8[n] = sum over in-edges of h0[src]   (8 lanes per node, fp32)
__global__ __launch_bounds__(256) void agg8(const float* __restrict__ h0, const int* __restrict__ rowptr,
                                            const int* __restrict__ csr, float* __restrict__ m8) {
    int tid = threadIdx.x;
    int n = blockIdx.x * 32 + (tid >> 3);
    int c = tid & 7;
    int s0 = rowptr[n], s1 = rowptr[n + 1];
    float acc = 0.f;
    for (int e = s0; e < s1; e++) {
        int s = csr[e];
        acc += h0[(size_t)s * IN_CH + c];
    }
    m8[(size_t)n * IN_CH + c] = acc;
}

// out = relu(m8 @ W1.T + b1)  [N,256] bf16
__global__ __launch_bounds__(256) void gemm1(const float* __restrict__ m8, const float* __restrict__ W1,
                                             const float* __restrict__ b1, u16* __restrict__ out) {
    __shared__ float ms[16][IN_CH];
    int n0 = blockIdx.x * 16;
    int tid = threadIdx.x;
    if (tid < 128) ms[tid >> 3][tid & 7] = m8[(size_t)(n0 + (tid >> 3)) * IN_CH + (tid & 7)];
    float w[IN_CH];
#pragma unroll
    for (int k = 0; k < IN_CH; k++) w[k] = W1[tid * IN_CH + k];
    float bo = b1[tid];
    __syncthreads();
#pragma unroll
    for (int i = 0; i < 16; i++) {
        float acc = bo;
#pragma unroll
        for (int k = 0; k < IN_CH; k++) acc += ms[i][k] * w[k];
        out[(size_t)(n0 + i) * EMB + tid] = f2b(fmaxf(acc, 0.f));
    }
}

// Pack W [256 out][256 in] fp32 into MFMA B-fragment order, bf16:
// Wsw[((nt*8+ks)*64 + lane)*8 + j] = bf16( W[nt*16+(lane&15)][ks*32+(lane>>4)*8+j] )
__global__ __launch_bounds__(256) void swizzle_w(const float* __restrict__ W, u16* __restrict__ Wsw) {
    int t = blockIdx.x * 256 + threadIdx.x;  // 8192 threads
    int lane = t & 63;
    int n = ((t >> 9) << 4) + (lane & 15);
    int k0 = (((t >> 6) & 7) << 5) + ((lane >> 4) << 3);
    u16 v[8];
#pragma unroll
    for (int j = 0; j < 8; j++) v[j] = f2b(W[(size_t)n * 256 + k0 + j]);
    ushort4* o = (ushort4*)&Wsw[(size_t)t * 8];
    o[0] = make_ushort4(v[0], v[1], v[2], v[3]);
    o[1] = make_ushort4(v[4], v[5], v[6], v[7]);
}

// ---------------- fused GCN layer ----------------
// Hout[r,:] = relu( (sum_{e: dst=r} Hin[src_e,:]) @ W.T + bias ) + Hin[r,:]
// Block = 4 waves x 16 rows. Wave-private LDS section (8 KB), XOR-swizzled
// (byte ^= (row&7)<<4) to kill the stride-512B bank conflict (G4).
__global__ __launch_bounds__(256) void fused_gcn(const u16* __restrict__ Hin,
                                                 const int* __restrict__ rowptr,
                                                 const int* __restrict__ csr,
                                                 const u16* __restrict__ Wsw,
                                                 const float* __restrict__ bias,
                                                 u16* __restrict__ Hout) {
    __shared__ __attribute__((aligned(16))) u16 lds[4][16][256];  // 32 KB
    const int wid = threadIdx.x >> 6;
    const int lane = threadIdx.x & 63;
    const int row0 = blockIdx.x * 64 + wid * 16;

    // ---- phase 1: aggregate 16 nodes into LDS (2 edges in flight, 16B/lane) ----
    const int half = lane >> 5;          // which edge of the pair
    const int c8b = (lane & 31) * 16;    // byte offset of this lane's 8 channels
    char* myLds = (char*)&lds[wid][0][0];
    for (int i = 0; i < 16; i++) {
        int n = row0 + i;
        int s0 = rowptr[n], s1 = rowptr[n + 1];
        float ac[8] = {0.f, 0.f, 0.f, 0.f, 0.f, 0.f, 0.f, 0.f};
        for (int e = s0 + half; e < s1; e += 2) {
            int s = csr[e];
            ushort8 v = *(const ushort8*)((const char*)Hin + (size_t)s * (EMB * 2) + c8b);
#pragma unroll
            for (int j = 0; j < 8; j++) ac[j] += b2f(v[j]);
        }
#pragma unroll
        for (int j = 0; j < 8; j++) ac[j] += __shfl_xor(ac[j], 32, 64);
        if (half == 0) {
            ushort8 o;
#pragma unroll
            for (int j = 0; j < 8; j++) o[j] = f2b(ac[j]);
            *(ushort8*)(myLds + i * 512 + (c8b ^ ((i & 7) << 4))) = o;
        }
    }

    // ---- phase 2: A fragments from LDS (wave-private, no barrier) ----
    const int m = lane & 15;
    const int g = lane >> 4;
    bf16x8 a[8];
#pragma unroll
    for (int ks = 0; ks < 8; ks++) {
        int boff = (g * 16 + ks * 64) ^ ((m & 7) << 4);
        a[ks] = *(const bf16x8*)(myLds + m * 512 + boff);
    }

    // ---- phase 3: MFMA 16 rows x 256 cols ----
    f32x4 acc[16];
#pragma unroll
    for (int nt = 0; nt < 16; nt++) acc[nt] = (f32x4){0.f, 0.f, 0.f, 0.f};
    const bf16x8* wp = (const bf16x8*)Wsw + lane;
#pragma unroll
    for (int nt = 0; nt < 16; nt++) {
        bf16x8 b[8];
#pragma unroll
        for (int ks = 0; ks < 8; ks++) b[ks] = wp[(nt * 8 + ks) * 64];
#pragma unroll
        for (int ks = 0; ks < 8; ks++)
            acc[nt] = __builtin_amdgcn_mfma_f32_16x16x32_bf16(a[ks], b[ks], acc[nt], 0, 0, 0);
    }

    // ---- phase 4: epilogue. C (col=lane&15, row=(lane>>4)*4+reg) -> LDS (bf16,
    // swizzled) -> coalesced ushort8 RMW vs Hin residual -> Hout.
#pragma unroll
    for (int nt = 0; nt < 16; nt++) {
#pragma unroll
        for (int r = 0; r < 4; r++) {
            int row = g * 4 + r;
            int cb = ((nt * 16 + m) * 2) ^ ((row & 7) << 4);
            *(u16*)(myLds + row * 512 + cb) = f2b(acc[nt][r]);
        }
    }
#pragma unroll
    for (int it = 0; it < 8; it++) {
        int row = it * 2 + (lane >> 5);
        int cb = ((lane & 31) * 16) ^ ((row & 7) << 4);
        ushort8 c = *(const ushort8*)(myLds + row * 512 + cb);
        int gcol = (lane & 31) * 8;
        size_t gidx = (size_t)(row0 + row) * EMB + gcol;
        ushort8 hres = *(const ushort8*)&Hin[gidx];
        float4 b0 = *(const float4*)&bias[gcol];
        float4 b1 = *(const float4*)&bias[gcol + 4];
        float bb[8] = {b0.x, b0.y, b0.z, b0.w, b1.x, b1.y, b1.z, b1.w};
        ushort8 o;
#pragma unroll
        for (int j = 0; j < 8; j++)
            o[j] = f2b(fmaxf(b2f(c[j]) + bb[j], 0.f) + b2f(hres[j]));
        *(ushort8*)&Hout[gidx] = o;
    }
}

// ---------------- pooling + head ----------------

__global__ void graph_bounds(const int* __restrict__ seg, int* __restrict__ gs, int n, int B) {
    int i = blockIdx.x * 256 + threadIdx.x;
    if (i >= n) return;
    int c = seg[i];
    int p = (i == 0) ? -1 : seg[i - 1];
    for (int b = p + 1; b <= c; b++) gs[b] = i;
    if (i == n - 1) {
        for (int b = c + 1; b <= B; b++) gs[b] = n;
    }
}

__global__ __launch_bounds__(256) void pool_kernel(const u16* __restrict__ h, const int* __restrict__ gs,
                                                   float* __restrict__ g) {
    int b = blockIdx.x, t = threadIdx.x;
    int s = gs[b], e = gs[b + 1];
    float acc = 0.f;
    for (int n = s; n < e; n++) acc += b2f(h[(size_t)n * EMB + t]);
    g[(size_t)b * EMB + t] = acc;
}

__global__ __launch_bounds__(128) void head_kernel(const float* __restrict__ g, const float* __restrict__ Wp1,
                                                   const float* __restrict__ Wp2, const float* __restrict__ bp2,
                                                   float* __restrict__ out) {
    __shared__ float gsm[EMB];
    __shared__ float red[HID];
    int b = blockIdx.x, t = threadIdx.x;
    gsm[t] = g[(size_t)b * EMB + t];
    gsm[t + 128] = g[(size_t)b * EMB + t + 128];
    __syncthreads();
    float acc = 0.f;
    const float* wr = &Wp1[(size_t)t * EMB];
#pragma unroll 4
    for (int k = 0; k < EMB; k++) acc += gsm[k] * wr[k];
    red[t] = fmaxf(acc, 0.f) * Wp2[t];
    __syncthreads();
    for (int off = 64; off > 0; off >>= 1) {
        if (t < off) red[t] += red[t + off];
        __syncthreads();
    }
    if (t == 0) out[b] = red[0] + bp2[0];
}

// ---------------- launch ----------------

extern "C" void kernel_launch(void* const* d_in, const int* in_sizes, int n_in,
                              void* d_out, int out_size, void* d_ws, size_t ws_size,
                              hipStream_t stream) {
    const float* x    = (const float*)d_in[0];
    const int*   src  = (const int*)d_in[1];
    const int*   dst  = (const int*)d_in[2];
    const int*   seg  = (const int*)d_in[3];
    const float* W_emb= (const float*)d_in[4];
    const float* W1   = (const float*)d_in[5];
    const float* b1   = (const float*)d_in[6];
    const float* W2   = (const float*)d_in[7];
    const float* b2   = (const float*)d_in[8];
    const float* W3   = (const float*)d_in[9];
    const float* b3   = (const float*)d_in[10];
    const float* Wp1  = (const float*)d_in[11];
    const float* Wp2  = (const float*)d_in[12];
    const float* bp2  = (const float*)d_in[13];
    float* out = (float*)d_out;

    char* ws = (char*)d_ws;
    size_t off = 0;
    auto alloc = [&](size_t bytes) -> void* {
        void* p = ws + off;
        off = (off + bytes + 255) & ~(size_t)255;
        return p;
    };
    const int N = N_NODES, E = N_EDGES, G = N_GRAPHS;
    float* h0   = (float*)alloc((size_t)N * IN_CH * 4);
    float* m8   = (float*)alloc((size_t)N * IN_CH * 4);
    u16* hA     = (u16*)alloc((size_t)N * EMB * 2);
    u16* hB     = (u16*)alloc((size_t)N * EMB * 2);
    u16* Wsw2   = (u16*)alloc(256 * 256 * 2);
    u16* Wsw3   = (u16*)alloc(256 * 256 * 2);
    int* rowptr = (int*)alloc((size_t)(N + 1) * 4);
    int* deg    = (int*)alloc((size_t)N * 4);
    int* csr    = (int*)alloc((size_t)E * 4);
    int* partials = (int*)alloc(1024 * 4);
    int* gs     = (int*)alloc((size_t)(G + 1) * 4);
    float* g    = (float*)alloc((size_t)G * EMB * 4);

    if (off > ws_size) return;  // clean failure instead of OOB crash

    // CSR build (by dst)
    hipMemsetAsync(deg, 0, (size_t)N * 4, stream);
    count_deg<<<E / 256, 256, 0, stream>>>(dst, deg, E);
    scan_a<<<196, 256, 0, stream>>>(deg, rowptr + 1, partials, N);
    scan_b<<<1, 256, 0, stream>>>(partials, 196);
    scan_c<<<782, 256, 0, stream>>>(rowptr, partials, N);
    hipMemsetAsync(deg, 0, (size_t)N * 4, stream);  // reuse as cursor
    fill_csr<<<E / 256, 256, 0, stream>>>(src, dst, rowptr, deg, csr, E);

    // layer 1
    emb_kernel<<<782, 256, 0, stream>>>(x, W_emb, h0, N);
    agg8<<<N / 32, 256, 0, stream>>>(h0, rowptr, csr, m8);
    gemm1<<<N / 16, 256, 0, stream>>>(m8, W1, b1, hA);

    swizzle_w<<<32, 256, 0, stream>>>(W2, Wsw2);
    swizzle_w<<<32, 256, 0, stream>>>(W3, Wsw3);

    // layer 2: hB = relu(agg(hA) @ W2.T + b2) + hA   (ping-pong: no in-place race)
    fused_gcn<<<N / 64, 256, 0, stream>>>(hA, rowptr, csr, Wsw2, b2, hB);
    // layer 3: hA = relu(agg(hB) @ W3.T + b3) + hB
    fused_gcn<<<N / 64, 256, 0, stream>>>(hB, rowptr, csr, Wsw3, b3, hA);

    // pooling + head
    graph_bounds<<<782, 256, 0, stream>>>(seg, gs, N, G);
    pool_kernel<<<G, 256, 0, stream>>>(hA, gs, g);
    head_kernel<<<G, 128, 0, stream>>>(g, Wp1, Wp2, bp2, out);
}

// Round 5
// 545.207 us; speedup vs baseline: 2.0886x; 1.1610x over previous
//
#include <hip/hip_runtime.h>
#include <hip/hip_bf16.h>

#define N_NODES 200000
#define N_EDGES 800000
#define N_GRAPHS 4000
#define D_N 35
#define IN_CH 8
#define EMB 256
#define HID 128

typedef unsigned short u16;
typedef __attribute__((ext_vector_type(8))) short bf16x8;
typedef __attribute__((ext_vector_type(8))) unsigned short ushort8;
typedef __attribute__((ext_vector_type(4))) float f32x4;

__device__ __forceinline__ float b2f(u16 u) {
    union { float f; unsigned v; } x; x.v = ((unsigned)u) << 16; return x.f;
}
__device__ __forceinline__ u16 f2b(float f) {
    union { float f; unsigned v; } x; x.f = f;
    unsigned r = x.v + 0x7fff + ((x.v >> 16) & 1);  // round-nearest-even
    return (u16)(r >> 16);
}

// ---------------- CSR build ----------------

__global__ void count_deg(const int* __restrict__ dst, int* __restrict__ deg, int n) {
    int e = blockIdx.x * 256 + threadIdx.x;
    if (e < n) atomicAdd(&deg[dst[e]], 1);
}

__global__ __launch_bounds__(256) void scan_a(const int* __restrict__ deg, int* __restrict__ incl1,
                                              int* __restrict__ partials, int n) {
    __shared__ int s[256];
    int tid = threadIdx.x;
    int base = blockIdx.x * 1024;
    int v[4]; int sum = 0;
#pragma unroll
    for (int j = 0; j < 4; j++) {
        int idx = base + tid * 4 + j;
        v[j] = (idx < n) ? deg[idx] : 0;
        sum += v[j];
    }
    s[tid] = sum; __syncthreads();
    for (int off = 1; off < 256; off <<= 1) {
        int t = (tid >= off) ? s[tid - off] : 0;
        __syncthreads();
        s[tid] += t;
        __syncthreads();
    }
    int run = s[tid] - sum;
#pragma unroll
    for (int j = 0; j < 4; j++) {
        int idx = base + tid * 4 + j;
        run += v[j];
        if (idx < n) incl1[idx] = run;
    }
    if (tid == 255) partials[blockIdx.x] = s[255];
}

__global__ __launch_bounds__(256) void scan_b(int* __restrict__ partials, int np) {
    __shared__ int s[256];
    int tid = threadIdx.x;
    int v = (tid < np) ? partials[tid] : 0;
    s[tid] = v; __syncthreads();
    for (int off = 1; off < 256; off <<= 1) {
        int t = (tid >= off) ? s[tid - off] : 0;
        __syncthreads();
        s[tid] += t;
        __syncthreads();
    }
    if (tid < np) partials[tid] = s[tid] - v;
}

__global__ void scan_c(int* __restrict__ rowptr, const int* __restrict__ partials, int n) {
    int i = blockIdx.x * 256 + threadIdx.x;
    if (i < n) rowptr[1 + i] += partials[i >> 10];
    if (i == 0) rowptr[0] = 0;
}

__global__ void fill_csr(const int* __restrict__ src, const int* __restrict__ dst,
                         const int* __restrict__ rowptr, int* __restrict__ cursor,
                         int* __restrict__ csr, int n) {
    int e = blockIdx.x * 256 + threadIdx.x;
    if (e >= n) return;
    int d = dst[e];
    int p = atomicAdd(&cursor[d], 1);
    csr[rowptr[d] + p] = src[e];
}

// ---------------- layer-1 feature pipeline ----------------

// h0 = x @ W_emb.T   [N,8]  (fp32)
__global__ __launch_bounds__(256) void emb_kernel(const float* __restrict__ x, const float* __restrict__ We,
                                                  float* __restrict__ h0, int n) {
    __shared__ float ws[IN_CH * D_N];
    int tid = threadIdx.x;
    for (int i = tid; i < IN_CH * D_N; i += 256) ws[i] = We[i];
    __syncthreads();
    int node = blockIdx.x * 256 + tid;
    if (node >= n) return;
    float xr[D_N];
    const float* xp = &x[(size_t)node * D_N];
#pragma unroll
    for (int k = 0; k < D_N; k++) xr[k] = xp[k];
#pragma unroll
    for (int j = 0; j < IN_CH; j++) {
        float acc = 0.f;
#pragma unroll
        for (int k = 0; k < D_N; k++) acc += xr[k] * ws[j * D_N + k];
        h0[(size_t)node * IN_CH + j] = acc;
    }
}

// m8[n] = sum over in-edges of h0[src]   (8 lanes per node, fp32)
__global__ __launch_bounds__(256) void agg8(const float* __restrict__ h0, const int* __restrict__ rowptr,
                                            const int* __restrict__ csr, float* __restrict__ m8) {
    int tid = threadIdx.x;
    int n = blockIdx.x * 32 + (tid >> 3);
    int c = tid & 7;
    int s0 = rowptr[n], s1 = rowptr[n + 1];
    float acc = 0.f;
    for (int e = s0; e < s1; e++) {
        int s = csr[e];
        acc += h0[(size_t)s * IN_CH + c];
    }
    m8[(size_t)n * IN_CH + c] = acc;
}

// out = relu(m8 @ W1.T + b1)  [N,256] bf16
__global__ __launch_bounds__(256) void gemm1(const float* __restrict__ m8, const float* __restrict__ W1,
                                             const float* __restrict__ b1, u16* __restrict__ out) {
    __shared__ float ms[16][IN_CH];
    int n0 = blockIdx.x * 16;
    int tid = threadIdx.x;
    if (tid < 128) ms[tid >> 3][tid & 7] = m8[(size_t)(n0 + (tid >> 3)) * IN_CH + (tid & 7)];
    float w[IN_CH];
#pragma unroll
    for (int k = 0; k < IN_CH; k++) w[k] = W1[tid * IN_CH + k];
    float bo = b1[tid];
    __syncthreads();
#pragma unroll
    for (int i = 0; i < 16; i++) {
        float acc = bo;
#pragma unroll
        for (int k = 0; k < IN_CH; k++) acc += ms[i][k] * w[k];
        out[(size_t)(n0 + i) * EMB + tid] = f2b(fmaxf(acc, 0.f));
    }
}

// Pack W [256 out][256 in] fp32 into MFMA B-fragment order, bf16:
// Wsw[((nt*8+ks)*64 + lane)*8 + j] = bf16( W[nt*16+(lane&15)][ks*32+(lane>>4)*8+j] )
__global__ __launch_bounds__(256) void swizzle_w(const float* __restrict__ W, u16* __restrict__ Wsw) {
    int t = blockIdx.x * 256 + threadIdx.x;  // 8192 threads
    int lane = t & 63;
    int n = ((t >> 9) << 4) + (lane & 15);
    int k0 = (((t >> 6) & 7) << 5) + ((lane >> 4) << 3);
    u16 v[8];
#pragma unroll
    for (int j = 0; j < 8; j++) v[j] = f2b(W[(size_t)n * 256 + k0 + j]);
    ushort4* o = (ushort4*)&Wsw[(size_t)t * 8];
    o[0] = make_ushort4(v[0], v[1], v[2], v[3]);
    o[1] = make_ushort4(v[4], v[5], v[6], v[7]);
}

// ---------------- fused GCN layer ----------------
// Hout[r,:] = relu( (sum_{e: dst=r} Hin[src_e,:]) @ W.T + bias ) + Hin[r,:]
// Block = 16 rows, 4 waves. Wave aggregates 4 rows CONCURRENTLY (branchless
// 4-wide independent gathers for MLP), all waves share one 8 KB LDS tile
// (XOR-swizzled byte ^= (row&7)<<4), each wave MFMAs 4 col-tiles.
__global__ __launch_bounds__(256) void fused_gcn(const u16* __restrict__ Hin,
                                                 const int* __restrict__ rowptr,
                                                 const int* __restrict__ csr,
                                                 const u16* __restrict__ Wsw,
                                                 const float* __restrict__ bias,
                                                 u16* __restrict__ Hout) {
    __shared__ __attribute__((aligned(16))) u16 lds[16][256];  // 8 KB
    const int wid = threadIdx.x >> 6;
    const int lane = threadIdx.x & 63;
    const int row0 = blockIdx.x * 16;
    char* ldsb = (char*)&lds[0][0];

    // ---- phase 1: wave wid aggregates rows rbase..rbase+3 into LDS ----
    const int half = lane >> 5;          // edge parity
    const int c8b = (lane & 31) * 16;    // byte offset of this lane's 8 channels
    const int rbase = row0 + wid * 4;
    int4 rpa = *(const int4*)&rowptr[rbase];
    int rp4 = rowptr[rbase + 4];
    int e0 = rpa.x + half, e1 = rpa.y + half, e2 = rpa.z + half, e3 = rpa.w + half;
    const int t0 = rpa.y, t1 = rpa.z, t2 = rpa.w, t3 = rp4;
    float ac0[8] = {0,0,0,0,0,0,0,0}, ac1[8] = {0,0,0,0,0,0,0,0};
    float ac2[8] = {0,0,0,0,0,0,0,0}, ac3[8] = {0,0,0,0,0,0,0,0};
    const char* hbase = (const char*)Hin;
    while (true) {
        bool p0 = e0 < t0, p1 = e1 < t1, p2 = e2 < t2, p3 = e3 < t3;
        if (!__any((int)(p0 | p1 | p2 | p3))) break;
        int i0 = csr[p0 ? e0 : 0], i1 = csr[p1 ? e1 : 0];
        int i2 = csr[p2 ? e2 : 0], i3 = csr[p3 ? e3 : 0];
        ushort8 v0 = *(const ushort8*)(hbase + (size_t)i0 * (EMB * 2) + c8b);
        ushort8 v1 = *(const ushort8*)(hbase + (size_t)i1 * (EMB * 2) + c8b);
        ushort8 v2 = *(const ushort8*)(hbase + (size_t)i2 * (EMB * 2) + c8b);
        ushort8 v3 = *(const ushort8*)(hbase + (size_t)i3 * (EMB * 2) + c8b);
        if (p0) {
#pragma unroll
            for (int j = 0; j < 8; j++) ac0[j] += b2f(v0[j]);
        }
        if (p1) {
#pragma unroll
            for (int j = 0; j < 8; j++) ac1[j] += b2f(v1[j]);
        }
        if (p2) {
#pragma unroll
            for (int j = 0; j < 8; j++) ac2[j] += b2f(v2[j]);
        }
        if (p3) {
#pragma unroll
            for (int j = 0; j < 8; j++) ac3[j] += b2f(v3[j]);
        }
        e0 += 2; e1 += 2; e2 += 2; e3 += 2;
    }
#pragma unroll
    for (int j = 0; j < 8; j++) {
        ac0[j] += __shfl_xor(ac0[j], 32, 64);
        ac1[j] += __shfl_xor(ac1[j], 32, 64);
        ac2[j] += __shfl_xor(ac2[j], 32, 64);
        ac3[j] += __shfl_xor(ac3[j], 32, 64);
    }
    if (half == 0) {
        ushort8 o0, o1, o2, o3;
#pragma unroll
        for (int j = 0; j < 8; j++) {
            o0[j] = f2b(ac0[j]); o1[j] = f2b(ac1[j]);
            o2[j] = f2b(ac2[j]); o3[j] = f2b(ac3[j]);
        }
        int li = wid * 4;
        *(ushort8*)(ldsb + (li + 0) * 512 + (c8b ^ (((li + 0) & 7) << 4))) = o0;
        *(ushort8*)(ldsb + (li + 1) * 512 + (c8b ^ (((li + 1) & 7) << 4))) = o1;
        *(ushort8*)(ldsb + (li + 2) * 512 + (c8b ^ (((li + 2) & 7) << 4))) = o2;
        *(ushort8*)(ldsb + (li + 3) * 512 + (c8b ^ (((li + 3) & 7) << 4))) = o3;
    }
    __syncthreads();

    // ---- phase 2: A fragments (all waves read the shared 16-row tile) ----
    const int m = lane & 15;
    const int g = lane >> 4;
    bf16x8 a[8];
#pragma unroll
    for (int ks = 0; ks < 8; ks++) {
        int boff = (g * 16 + ks * 64) ^ ((m & 7) << 4);
        a[ks] = *(const bf16x8*)(ldsb + m * 512 + boff);
    }
    __syncthreads();  // all a-reads done before C overwrites LDS

    // ---- phase 3: MFMA, wave owns col-tiles wid*4 .. wid*4+3 ----
    f32x4 acc[4];
#pragma unroll
    for (int t = 0; t < 4; t++) acc[t] = (f32x4){0.f, 0.f, 0.f, 0.f};
    const bf16x8* wp = (const bf16x8*)Wsw + lane;
#pragma unroll
    for (int t = 0; t < 4; t++) {
        int nt = wid * 4 + t;
        bf16x8 b[8];
#pragma unroll
        for (int ks = 0; ks < 8; ks++) b[ks] = wp[(nt * 8 + ks) * 64];
#pragma unroll
        for (int ks = 0; ks < 8; ks++)
            acc[t] = __builtin_amdgcn_mfma_f32_16x16x32_bf16(a[ks], b[ks], acc[t], 0, 0, 0);
    }

    // ---- phase 4: C -> LDS (bf16, swizzled); C layout col=lane&15, row=(lane>>4)*4+reg ----
#pragma unroll
    for (int t = 0; t < 4; t++) {
        int col = (wid * 4 + t) * 16 + m;
#pragma unroll
        for (int r = 0; r < 4; r++) {
            int row = g * 4 + r;
            *(u16*)(ldsb + row * 512 + ((col * 2) ^ ((row & 7) << 4))) = f2b(acc[t][r]);
        }
    }
    __syncthreads();

    // ---- phase 5: cooperative coalesced epilogue (relu + bias + residual) ----
    {
        int row = threadIdx.x >> 4;           // 0..15
        int cb0 = (threadIdx.x & 15) * 16;    // 0..240
#pragma unroll
        for (int p = 0; p < 2; p++) {
            int cb = cb0 + p * 256;
            ushort8 c = *(const ushort8*)(ldsb + row * 512 + (cb ^ ((row & 7) << 4)));
            int gcol = cb >> 1;
            size_t gidx = (size_t)(row0 + row) * EMB + gcol;
            ushort8 hres = *(const ushort8*)&Hin[gidx];
            float4 bq0 = *(const float4*)&bias[gcol];
            float4 bq1 = *(const float4*)&bias[gcol + 4];
            float bb[8] = {bq0.x, bq0.y, bq0.z, bq0.w, bq1.x, bq1.y, bq1.z, bq1.w};
            ushort8 o;
#pragma unroll
            for (int j = 0; j < 8; j++)
                o[j] = f2b(fmaxf(b2f(c[j]) + bb[j], 0.f) + b2f(hres[j]));
            *(ushort8*)&Hout[gidx] = o;
        }
    }
}

// ---------------- pooling + head ----------------

__global__ void graph_bounds(const int* __restrict__ seg, int* __restrict__ gs, int n, int B) {
    int i = blockIdx.x * 256 + threadIdx.x;
    if (i >= n) return;
    int c = seg[i];
    int p = (i == 0) ? -1 : seg[i - 1];
    for (int b = p + 1; b <= c; b++) gs[b] = i;
    if (i == n - 1) {
        for (int b = c + 1; b <= B; b++) gs[b] = n;
    }
}

__global__ __launch_bounds__(256) void pool_kernel(const u16* __restrict__ h, const int* __restrict__ gs,
                                                   float* __restrict__ g) {
    int b = blockIdx.x, t = threadIdx.x;
    int s = gs[b], e = gs[b + 1];
    float acc = 0.f;
    for (int n = s; n < e; n++) acc += b2f(h[(size_t)n * EMB + t]);
    g[(size_t)b * EMB + t] = acc;
}

__global__ __launch_bounds__(128) void head_kernel(const float* __restrict__ g, const float* __restrict__ Wp1,
                                                   const float* __restrict__ Wp2, const float* __restrict__ bp2,
                                                   float* __restrict__ out) {
    __shared__ float gsm[EMB];
    __shared__ float red[HID];
    int b = blockIdx.x, t = threadIdx.x;
    gsm[t] = g[(size_t)b * EMB + t];
    gsm[t + 128] = g[(size_t)b * EMB + t + 128];
    __syncthreads();
    float acc = 0.f;
    const float* wr = &Wp1[(size_t)t * EMB];
#pragma unroll 4
    for (int k = 0; k < EMB; k++) acc += gsm[k] * wr[k];
    red[t] = fmaxf(acc, 0.f) * Wp2[t];
    __syncthreads();
    for (int off = 64; off > 0; off >>= 1) {
        if (t < off) red[t] += red[t + off];
        __syncthreads();
    }
    if (t == 0) out[b] = red[0] + bp2[0];
}

// ---------------- launch ----------------

extern "C" void kernel_launch(void* const* d_in, const int* in_sizes, int n_in,
                              void* d_out, int out_size, void* d_ws, size_t ws_size,
                              hipStream_t stream) {
    const float* x    = (const float*)d_in[0];
    const int*   src  = (const int*)d_in[1];
    const int*   dst  = (const int*)d_in[2];
    const int*   seg  = (const int*)d_in[3];
    const float* W_emb= (const float*)d_in[4];
    const float* W1   = (const float*)d_in[5];
    const float* b1   = (const float*)d_in[6];
    const float* W2   = (const float*)d_in[7];
    const float* b2   = (const float*)d_in[8];
    const float* W3   = (const float*)d_in[9];
    const float* b3   = (const float*)d_in[10];
    const float* Wp1  = (const float*)d_in[11];
    const float* Wp2  = (const float*)d_in[12];
    const float* bp2  = (const float*)d_in[13];
    float* out = (float*)d_out;

    char* ws = (char*)d_ws;
    size_t off = 0;
    auto alloc = [&](size_t bytes) -> void* {
        void* p = ws + off;
        off = (off + bytes + 255) & ~(size_t)255;
        return p;
    };
    const int N = N_NODES, E = N_EDGES, G = N_GRAPHS;
    float* h0   = (float*)alloc((size_t)N * IN_CH * 4);
    float* m8   = (float*)alloc((size_t)N * IN_CH * 4);
    u16* hA     = (u16*)alloc((size_t)N * EMB * 2);
    u16* hB     = (u16*)alloc((size_t)N * EMB * 2);
    u16* Wsw2   = (u16*)alloc(256 * 256 * 2);
    u16* Wsw3   = (u16*)alloc(256 * 256 * 2);
    int* rowptr = (int*)alloc((size_t)(N + 1) * 4);
    int* deg    = (int*)alloc((size_t)N * 4);
    int* csr    = (int*)alloc((size_t)E * 4);
    int* partials = (int*)alloc(1024 * 4);
    int* gs     = (int*)alloc((size_t)(G + 1) * 4);
    float* g    = (float*)alloc((size_t)G * EMB * 4);

    if (off > ws_size) return;  // clean failure instead of OOB crash

    // CSR build (by dst)
    hipMemsetAsync(deg, 0, (size_t)N * 4, stream);
    count_deg<<<E / 256, 256, 0, stream>>>(dst, deg, E);
    scan_a<<<196, 256, 0, stream>>>(deg, rowptr + 1, partials, N);
    scan_b<<<1, 256, 0, stream>>>(partials, 196);
    scan_c<<<782, 256, 0, stream>>>(rowptr, partials, N);
    hipMemsetAsync(deg, 0, (size_t)N * 4, stream);  // reuse as cursor
    fill_csr<<<E / 256, 256, 0, stream>>>(src, dst, rowptr, deg, csr, E);

    // layer 1
    emb_kernel<<<782, 256, 0, stream>>>(x, W_emb, h0, N);
    agg8<<<N / 32, 256, 0, stream>>>(h0, rowptr, csr, m8);
    gemm1<<<N / 16, 256, 0, stream>>>(m8, W1, b1, hA);

    swizzle_w<<<32, 256, 0, stream>>>(W2, Wsw2);
    swizzle_w<<<32, 256, 0, stream>>>(W3, Wsw3);

    // layer 2: hB = relu(agg(hA) @ W2.T + b2) + hA   (ping-pong)
    fused_gcn<<<N / 16, 256, 0, stream>>>(hA, rowptr, csr, Wsw2, b2, hB);
    // layer 3: hA = relu(agg(hB) @ W3.T + b3) + hB
    fused_gcn<<<N / 16, 256, 0, stream>>>(hB, rowptr, csr, Wsw3, b3, hA);

    // pooling + head
    graph_bounds<<<782, 256, 0, stream>>>(seg, gs, N, G);
    pool_kernel<<<G, 256, 0, stream>>>(hA, gs, g);
    head_kernel<<<G, 128, 0, stream>>>(g, Wp1, Wp2, bp2, out);
}

// Round 6
// 525.774 us; speedup vs baseline: 2.1658x; 1.0370x over previous
//
#include <hip/hip_runtime.h>
#include <hip/hip_bf16.h>

#define N_NODES 200000
#define N_EDGES 800000
#define N_GRAPHS 4000
#define D_N 35
#define IN_CH 8
#define EMB 256
#define HID 128

typedef unsigned short u16;
typedef __attribute__((ext_vector_type(8))) short bf16x8;
typedef __attribute__((ext_vector_type(8))) unsigned short ushort8;
typedef __attribute__((ext_vector_type(4))) float f32x4;

__device__ __forceinline__ float b2f(u16 u) {
    union { float f; unsigned v; } x; x.v = ((unsigned)u) << 16; return x.f;
}
__device__ __forceinline__ u16 f2b(float f) {
    union { float f; unsigned v; } x; x.f = f;
    unsigned r = x.v + 0x7fff + ((x.v >> 16) & 1);  // round-nearest-even
    return (u16)(r >> 16);
}
__device__ __forceinline__ int clampe(int e, int t) {
    int v = e < t ? e : (t - 1);
    return v < 0 ? 0 : v;
}

// ---------------- CSR build ----------------

__global__ void count_deg(const int* __restrict__ dst, int* __restrict__ deg, int n) {
    int e = blockIdx.x * 256 + threadIdx.x;
    if (e < n) atomicAdd(&deg[dst[e]], 1);
}

__global__ __launch_bounds__(256) void scan_a(const int* __restrict__ deg, int* __restrict__ incl1,
                                              int* __restrict__ partials, int n) {
    __shared__ int s[256];
    int tid = threadIdx.x;
    int base = blockIdx.x * 1024;
    int v[4]; int sum = 0;
#pragma unroll
    for (int j = 0; j < 4; j++) {
        int idx = base + tid * 4 + j;
        v[j] = (idx < n) ? deg[idx] : 0;
        sum += v[j];
    }
    s[tid] = sum; __syncthreads();
    for (int off = 1; off < 256; off <<= 1) {
        int t = (tid >= off) ? s[tid - off] : 0;
        __syncthreads();
        s[tid] += t;
        __syncthreads();
    }
    int run = s[tid] - sum;
#pragma unroll
    for (int j = 0; j < 4; j++) {
        int idx = base + tid * 4 + j;
        run += v[j];
        if (idx < n) incl1[idx] = run;
    }
    if (tid == 255) partials[blockIdx.x] = s[255];
}

__global__ __launch_bounds__(256) void scan_b(int* __restrict__ partials, int np) {
    __shared__ int s[256];
    int tid = threadIdx.x;
    int v = (tid < np) ? partials[tid] : 0;
    s[tid] = v; __syncthreads();
    for (int off = 1; off < 256; off <<= 1) {
        int t = (tid >= off) ? s[tid - off] : 0;
        __syncthreads();
        s[tid] += t;
        __syncthreads();
    }
    if (tid < np) partials[tid] = s[tid] - v;
}

__global__ void scan_c(int* __restrict__ rowptr, const int* __restrict__ partials, int n) {
    int i = blockIdx.x * 256 + threadIdx.x;
    if (i < n) rowptr[1 + i] += partials[i >> 10];
    if (i == 0) rowptr[0] = 0;
}

__global__ void fill_csr(const int* __restrict__ src, const int* __restrict__ dst,
                         const int* __restrict__ rowptr, int* __restrict__ cursor,
                         int* __restrict__ csr, int n) {
    int e = blockIdx.x * 256 + threadIdx.x;
    if (e >= n) return;
    int d = dst[e];
    int p = atomicAdd(&cursor[d], 1);
    csr[rowptr[d] + p] = src[e];
}

// ---------------- weight packing ----------------

// W [256 out][256 in] fp32 -> MFMA B-fragment order bf16:
// Wsw[((nt*8+ks)*64 + lane)*8 + j] = bf16( W[nt*16+(lane&15)][ks*32+(lane>>4)*8+j] )
__global__ __launch_bounds__(256) void swizzle_w(const float* __restrict__ W, u16* __restrict__ Wsw) {
    int t = blockIdx.x * 256 + threadIdx.x;  // 8192 threads
    int lane = t & 63;
    int n = ((t >> 9) << 4) + (lane & 15);
    int k0 = (((t >> 6) & 7) << 5) + ((lane >> 4) << 3);
    u16 v[8];
#pragma unroll
    for (int j = 0; j < 8; j++) v[j] = f2b(W[(size_t)n * 256 + k0 + j]);
    ushort4* o = (ushort4*)&Wsw[(size_t)t * 8];
    o[0] = make_ushort4(v[0], v[1], v[2], v[3]);
    o[1] = make_ushort4(v[4], v[5], v[6], v[7]);
}

// Wc = W1[256,8] @ We[8,35], zero-padded to K=64, packed into B-fragment order.
__global__ __launch_bounds__(256) void swizzle_wc(const float* __restrict__ W1, const float* __restrict__ We,
                                                  u16* __restrict__ Wsw) {
    int t = blockIdx.x * 256 + threadIdx.x;  // 2048 threads
    int lane = t & 63;
    int nt = t >> 7;
    int ks = (t >> 6) & 1;
    int n = nt * 16 + (lane & 15);
    int k0 = ks * 32 + ((lane >> 4) << 3);
    float w1r[8];
#pragma unroll
    for (int i = 0; i < 8; i++) w1r[i] = W1[n * 8 + i];
    u16 v[8];
#pragma unroll
    for (int j = 0; j < 8; j++) {
        int k = k0 + j;
        float acc = 0.f;
        if (k < D_N) {
#pragma unroll
            for (int i = 0; i < 8; i++) acc += w1r[i] * We[i * D_N + k];
        }
        v[j] = f2b(acc);
    }
    ushort4* o = (ushort4*)&Wsw[(size_t)t * 8];
    o[0] = make_ushort4(v[0], v[1], v[2], v[3]);
    o[1] = make_ushort4(v[4], v[5], v[6], v[7]);
}

// ---------------- fused layer 1 ----------------
// Hout[r,:] = relu( (sum_{e: dst=r} x[src_e,:35]) @ Wc.T + b1 ), K padded to 64.
__global__ __launch_bounds__(256) void fused_gcn1(const float* __restrict__ x,
                                                  const int* __restrict__ rowptr,
                                                  const int* __restrict__ csr,
                                                  const u16* __restrict__ Wsw1,
                                                  const float* __restrict__ bias,
                                                  u16* __restrict__ Hout) {
    __shared__ __attribute__((aligned(16))) u16 lds[16][256];  // 8 KB (phase1 uses a [16][64] region)
    const int wid = threadIdx.x >> 6;
    const int lane = threadIdx.x & 63;
    const int row0 = blockIdx.x * 16;
    char* ldsb = (char*)lds;

    // ---- phase 1: gather-sum x rows (fp32 exact) ----
    const int half = lane >> 5;
    const int cid = lane & 31;                     // main channel (0..31)
    const int xe = (cid < 3) ? 32 + cid : 34;      // extra channel (32..34), clamped
    const int rbase = row0 + wid * 4;
    int4 rpa = *(const int4*)&rowptr[rbase];
    int rp4 = rowptr[rbase + 4];
    int e0 = rpa.x + half, e1 = rpa.y + half, e2 = rpa.z + half, e3 = rpa.w + half;
    const int t0 = rpa.y, t1 = rpa.z, t2 = rpa.w, t3 = rp4;
    int i0 = csr[clampe(e0, t0)], i1 = csr[clampe(e1, t1)];
    int i2 = csr[clampe(e2, t2)], i3 = csr[clampe(e3, t3)];
    float am0 = 0.f, am1 = 0.f, am2 = 0.f, am3 = 0.f;
    float ax0 = 0.f, ax1 = 0.f, ax2 = 0.f, ax3 = 0.f;
    bool p0 = e0 < t0, p1 = e1 < t1, p2 = e2 < t2, p3 = e3 < t3;
    while (__any((int)(p0 | p1 | p2 | p3))) {
        const float* r0p = x + (size_t)i0 * D_N;
        const float* r1p = x + (size_t)i1 * D_N;
        const float* r2p = x + (size_t)i2 * D_N;
        const float* r3p = x + (size_t)i3 * D_N;
        float v0 = r0p[cid], w0 = r0p[xe];
        float v1 = r1p[cid], w1 = r1p[xe];
        float v2 = r2p[cid], w2 = r2p[xe];
        float v3 = r3p[cid], w3 = r3p[xe];
        e0 += 2; e1 += 2; e2 += 2; e3 += 2;
        int j0 = csr[clampe(e0, t0)], j1 = csr[clampe(e1, t1)];
        int j2 = csr[clampe(e2, t2)], j3 = csr[clampe(e3, t3)];
        if (p0) { am0 += v0; ax0 += w0; }
        if (p1) { am1 += v1; ax1 += w1; }
        if (p2) { am2 += v2; ax2 += w2; }
        if (p3) { am3 += v3; ax3 += w3; }
        i0 = j0; i1 = j1; i2 = j2; i3 = j3;
        p0 = e0 < t0; p1 = e1 < t1; p2 = e2 < t2; p3 = e3 < t3;
    }
    am0 += __shfl_xor(am0, 32, 64); ax0 += __shfl_xor(ax0, 32, 64);
    am1 += __shfl_xor(am1, 32, 64); ax1 += __shfl_xor(ax1, 32, 64);
    am2 += __shfl_xor(am2, 32, 64); ax2 += __shfl_xor(ax2, 32, 64);
    am3 += __shfl_xor(am3, 32, 64); ax3 += __shfl_xor(ax3, 32, 64);
    if (half == 0) {
        float ams[4] = {am0, am1, am2, am3};
        float axs[4] = {ax0, ax1, ax2, ax3};
#pragma unroll
        for (int j = 0; j < 4; j++) {
            int li = wid * 4 + j;
            int sw = (li & 7) << 4;
            *(u16*)(ldsb + li * 128 + ((cid * 2) ^ sw)) = f2b(ams[j]);
            u16 zv = (cid < 3) ? f2b(axs[j]) : (u16)0;
            *(u16*)(ldsb + li * 128 + (((32 + cid) * 2) ^ sw)) = zv;
        }
    }
    __syncthreads();

    // ---- phase 2: A fragments (K=64, [16][64] tile, stride 128B, swizzled) ----
    const int m = lane & 15;
    const int g = lane >> 4;
    bf16x8 a[2];
#pragma unroll
    for (int ks = 0; ks < 2; ks++) {
        int boff = (ks * 64 + g * 16) ^ ((m & 7) << 4);
        a[ks] = *(const bf16x8*)(ldsb + m * 128 + boff);
    }
    __syncthreads();

    // ---- phase 3: MFMA, wave owns col-tiles wid*4..wid*4+3 ----
    f32x4 acc[4];
#pragma unroll
    for (int t = 0; t < 4; t++) acc[t] = (f32x4){0.f, 0.f, 0.f, 0.f};
    const bf16x8* wp = (const bf16x8*)Wsw1 + lane;
#pragma unroll
    for (int t = 0; t < 4; t++) {
        int nt = wid * 4 + t;
        bf16x8 b0 = wp[(nt * 2 + 0) * 64];
        bf16x8 b1 = wp[(nt * 2 + 1) * 64];
        acc[t] = __builtin_amdgcn_mfma_f32_16x16x32_bf16(a[0], b0, acc[t], 0, 0, 0);
        acc[t] = __builtin_amdgcn_mfma_f32_16x16x32_bf16(a[1], b1, acc[t], 0, 0, 0);
    }

    // ---- phase 4: C -> LDS (bf16, swizzled, rows stride 512B) ----
#pragma unroll
    for (int t = 0; t < 4; t++) {
        int col = (wid * 4 + t) * 16 + m;
#pragma unroll
        for (int r = 0; r < 4; r++) {
            int row = g * 4 + r;
            *(u16*)(ldsb + row * 512 + ((col * 2) ^ ((row & 7) << 4))) = f2b(acc[t][r]);
        }
    }
    __syncthreads();

    // ---- phase 5: epilogue relu + bias (no residual) ----
    {
        int row = threadIdx.x >> 4;
        int cb0 = (threadIdx.x & 15) * 16;
#pragma unroll
        for (int p = 0; p < 2; p++) {
            int cb = cb0 + p * 256;
            ushort8 c = *(const ushort8*)(ldsb + row * 512 + (cb ^ ((row & 7) << 4)));
            int gcol = cb >> 1;
            size_t gidx = (size_t)(row0 + row) * EMB + gcol;
            float4 bq0 = *(const float4*)&bias[gcol];
            float4 bq1 = *(const float4*)&bias[gcol + 4];
            float bb[8] = {bq0.x, bq0.y, bq0.z, bq0.w, bq1.x, bq1.y, bq1.z, bq1.w};
            ushort8 o;
#pragma unroll
            for (int j = 0; j < 8; j++)
                o[j] = f2b(fmaxf(b2f(c[j]) + bb[j], 0.f));
            *(ushort8*)&Hout[gidx] = o;
        }
    }
}

// ---------------- fused GCN layer (2,3) ----------------
// Hout[r,:] = relu( (sum_{e: dst=r} Hin[src_e,:]) @ W.T + bias ) + Hin[r,:]
__global__ __launch_bounds__(256) void fused_gcn(const u16* __restrict__ Hin,
                                                 const int* __restrict__ rowptr,
                                                 const int* __restrict__ csr,
                                                 const u16* __restrict__ Wsw,
                                                 const float* __restrict__ bias,
                                                 u16* __restrict__ Hout) {
    __shared__ __attribute__((aligned(16))) u16 lds[16][256];  // 8 KB
    const int wid = threadIdx.x >> 6;
    const int lane = threadIdx.x & 63;
    const int row0 = blockIdx.x * 16;
    char* ldsb = (char*)lds;
    const char* hbase = (const char*)Hin;

    // residual prefetch (registers; epilogue-matching layout)
    const int rrow = threadIdx.x >> 4;
    const int rcb = (threadIdx.x & 15) * 16;
    ushort8 res0 = *(const ushort8*)(hbase + (size_t)(row0 + rrow) * 512 + rcb);
    ushort8 res1 = *(const ushort8*)(hbase + (size_t)(row0 + rrow) * 512 + rcb + 256);

    // ---- phase 1: gather with csr prefetched one iteration ahead ----
    const int half = lane >> 5;
    const int c8b = (lane & 31) * 16;
    const int rbase = row0 + wid * 4;
    int4 rpa = *(const int4*)&rowptr[rbase];
    int rp4 = rowptr[rbase + 4];
    int e0 = rpa.x + half, e1 = rpa.y + half, e2 = rpa.z + half, e3 = rpa.w + half;
    const int t0 = rpa.y, t1 = rpa.z, t2 = rpa.w, t3 = rp4;
    int i0 = csr[clampe(e0, t0)], i1 = csr[clampe(e1, t1)];
    int i2 = csr[clampe(e2, t2)], i3 = csr[clampe(e3, t3)];
    float2 ac0[4], ac1[4], ac2[4], ac3[4];
#pragma unroll
    for (int j = 0; j < 4; j++) {
        ac0[j] = make_float2(0.f, 0.f); ac1[j] = make_float2(0.f, 0.f);
        ac2[j] = make_float2(0.f, 0.f); ac3[j] = make_float2(0.f, 0.f);
    }
    bool p0 = e0 < t0, p1 = e1 < t1, p2 = e2 < t2, p3 = e3 < t3;
    while (__any((int)(p0 | p1 | p2 | p3))) {
        ushort8 v0 = *(const ushort8*)(hbase + (size_t)i0 * (EMB * 2) + c8b);
        ushort8 v1 = *(const ushort8*)(hbase + (size_t)i1 * (EMB * 2) + c8b);
        ushort8 v2 = *(const ushort8*)(hbase + (size_t)i2 * (EMB * 2) + c8b);
        ushort8 v3 = *(const ushort8*)(hbase + (size_t)i3 * (EMB * 2) + c8b);
        e0 += 2; e1 += 2; e2 += 2; e3 += 2;
        int j0 = csr[clampe(e0, t0)], j1 = csr[clampe(e1, t1)];
        int j2 = csr[clampe(e2, t2)], j3 = csr[clampe(e3, t3)];
        if (p0) {
#pragma unroll
            for (int j = 0; j < 4; j++) { ac0[j].x += b2f(v0[2 * j]); ac0[j].y += b2f(v0[2 * j + 1]); }
        }
        if (p1) {
#pragma unroll
            for (int j = 0; j < 4; j++) { ac1[j].x += b2f(v1[2 * j]); ac1[j].y += b2f(v1[2 * j + 1]); }
        }
        if (p2) {
#pragma unroll
            for (int j = 0; j < 4; j++) { ac2[j].x += b2f(v2[2 * j]); ac2[j].y += b2f(v2[2 * j + 1]); }
        }
        if (p3) {
#pragma unroll
            for (int j = 0; j < 4; j++) { ac3[j].x += b2f(v3[2 * j]); ac3[j].y += b2f(v3[2 * j + 1]); }
        }
        i0 = j0; i1 = j1; i2 = j2; i3 = j3;
        p0 = e0 < t0; p1 = e1 < t1; p2 = e2 < t2; p3 = e3 < t3;
    }
#pragma unroll
    for (int j = 0; j < 4; j++) {
        ac0[j].x += __shfl_xor(ac0[j].x, 32, 64); ac0[j].y += __shfl_xor(ac0[j].y, 32, 64);
        ac1[j].x += __shfl_xor(ac1[j].x, 32, 64); ac1[j].y += __shfl_xor(ac1[j].y, 32, 64);
        ac2[j].x += __shfl_xor(ac2[j].x, 32, 64); ac2[j].y += __shfl_xor(ac2[j].y, 32, 64);
        ac3[j].x += __shfl_xor(ac3[j].x, 32, 64); ac3[j].y += __shfl_xor(ac3[j].y, 32, 64);
    }
    if (half == 0) {
        ushort8 o0, o1, o2, o3;
#pragma unroll
        for (int j = 0; j < 4; j++) {
            o0[2 * j] = f2b(ac0[j].x); o0[2 * j + 1] = f2b(ac0[j].y);
            o1[2 * j] = f2b(ac1[j].x); o1[2 * j + 1] = f2b(ac1[j].y);
            o2[2 * j] = f2b(ac2[j].x); o2[2 * j + 1] = f2b(ac2[j].y);
            o3[2 * j] = f2b(ac3[j].x); o3[2 * j + 1] = f2b(ac3[j].y);
        }
        int li = wid * 4;
        *(ushort8*)(ldsb + (li + 0) * 512 + (c8b ^ (((li + 0) & 7) << 4))) = o0;
        *(ushort8*)(ldsb + (li + 1) * 512 + (c8b ^ (((li + 1) & 7) << 4))) = o1;
        *(ushort8*)(ldsb + (li + 2) * 512 + (c8b ^ (((li + 2) & 7) << 4))) = o2;
        *(ushort8*)(ldsb + (li + 3) * 512 + (c8b ^ (((li + 3) & 7) << 4))) = o3;
    }
    __syncthreads();

    // ---- phase 2: A fragments ----
    const int m = lane & 15;
    const int g = lane >> 4;
    bf16x8 a[8];
#pragma unroll
    for (int ks = 0; ks < 8; ks++) {
        int boff = (g * 16 + ks * 64) ^ ((m & 7) << 4);
        a[ks] = *(const bf16x8*)(ldsb + m * 512 + boff);
    }
    __syncthreads();

    // ---- phase 3: MFMA, wave owns col-tiles wid*4..wid*4+3 ----
    f32x4 acc[4];
#pragma unroll
    for (int t = 0; t < 4; t++) acc[t] = (f32x4){0.f, 0.f, 0.f, 0.f};
    const bf16x8* wp = (const bf16x8*)Wsw + lane;
#pragma unroll
    for (int t = 0; t < 4; t++) {
        int nt = wid * 4 + t;
        bf16x8 b[8];
#pragma unroll
        for (int ks = 0; ks < 8; ks++) b[ks] = wp[(nt * 8 + ks) * 64];
#pragma unroll
        for (int ks = 0; ks < 8; ks++)
            acc[t] = __builtin_amdgcn_mfma_f32_16x16x32_bf16(a[ks], b[ks], acc[t], 0, 0, 0);
    }

    // ---- phase 4: C -> LDS (bf16, swizzled) ----
#pragma unroll
    for (int t = 0; t < 4; t++) {
        int col = (wid * 4 + t) * 16 + m;
#pragma unroll
        for (int r = 0; r < 4; r++) {
            int row = g * 4 + r;
            *(u16*)(ldsb + row * 512 + ((col * 2) ^ ((row & 7) << 4))) = f2b(acc[t][r]);
        }
    }
    __syncthreads();

    // ---- phase 5: epilogue relu + bias + prefetched residual ----
    {
        int row = threadIdx.x >> 4;
        int cb0 = (threadIdx.x & 15) * 16;
        ushort8 resv[2] = {res0, res1};
#pragma unroll
        for (int p = 0; p < 2; p++) {
            int cb = cb0 + p * 256;
            ushort8 c = *(const ushort8*)(ldsb + row * 512 + (cb ^ ((row & 7) << 4)));
            int gcol = cb >> 1;
            size_t gidx = (size_t)(row0 + row) * EMB + gcol;
            float4 bq0 = *(const float4*)&bias[gcol];
            float4 bq1 = *(const float4*)&bias[gcol + 4];
            float bb[8] = {bq0.x, bq0.y, bq0.z, bq0.w, bq1.x, bq1.y, bq1.z, bq1.w};
            ushort8 o;
#pragma unroll
            for (int j = 0; j < 8; j++)
                o[j] = f2b(fmaxf(b2f(c[j]) + bb[j], 0.f) + b2f(resv[p][j]));
            *(ushort8*)&Hout[gidx] = o;
        }
    }
}

// ---------------- pooling + head (fused) ----------------

__global__ void graph_bounds(const int* __restrict__ seg, int* __restrict__ gs, int n, int B) {
    int i = blockIdx.x * 256 + threadIdx.x;
    if (i >= n) return;
    int c = seg[i];
    int p = (i == 0) ? -1 : seg[i - 1];
    for (int b = p + 1; b <= c; b++) gs[b] = i;
    if (i == n - 1) {
        for (int b = c + 1; b <= B; b++) gs[b] = n;
    }
}

__global__ __launch_bounds__(256) void pool_head(const u16* __restrict__ h, const int* __restrict__ gs,
                                                 const float* __restrict__ Wp1, const float* __restrict__ Wp2,
                                                 const float* __restrict__ bp2, float* __restrict__ out) {
    __shared__ float gp[EMB];
    __shared__ float red[HID];
    int b = blockIdx.x, t = threadIdx.x;
    int s = gs[b], e = gs[b + 1];
    int half = t >> 7, cp = (t & 127) * 2;
    float a0 = 0.f, a1 = 0.f;
    for (int r = s + half; r < e; r += 2) {
        ushort2 v = *(const ushort2*)&h[(size_t)r * EMB + cp];
        a0 += b2f(v.x); a1 += b2f(v.y);
    }
    if (half == 0) { gp[cp] = a0; gp[cp + 1] = a1; }
    __syncthreads();
    if (half == 1) { gp[cp] += a0; gp[cp + 1] += a1; }
    __syncthreads();
    if (t < HID) {
        float acc = 0.f;
        const float4* wr = (const float4*)&Wp1[(size_t)t * EMB];
        const float4* gp4 = (const float4*)gp;
#pragma unroll 8
        for (int k = 0; k < EMB / 4; k++) {
            float4 w = wr[k], gg = gp4[k];
            acc += w.x * gg.x + w.y * gg.y + w.z * gg.z + w.w * gg.w;
        }
        red[t] = fmaxf(acc, 0.f) * Wp2[t];
    }
    __syncthreads();
    for (int off = 64; off > 0; off >>= 1) {
        if (t < off) red[t] += red[t + off];
        __syncthreads();
    }
    if (t == 0) out[b] = red[0] + bp2[0];
}

// ---------------- launch ----------------

extern "C" void kernel_launch(void* const* d_in, const int* in_sizes, int n_in,
                              void* d_out, int out_size, void* d_ws, size_t ws_size,
                              hipStream_t stream) {
    const float* x    = (const float*)d_in[0];
    const int*   src  = (const int*)d_in[1];
    const int*   dst  = (const int*)d_in[2];
    const int*   seg  = (const int*)d_in[3];
    const float* W_emb= (const float*)d_in[4];
    const float* W1   = (const float*)d_in[5];
    const float* b1   = (const float*)d_in[6];
    const float* W2   = (const float*)d_in[7];
    const float* b2   = (const float*)d_in[8];
    const float* W3   = (const float*)d_in[9];
    const float* b3   = (const float*)d_in[10];
    const float* Wp1  = (const float*)d_in[11];
    const float* Wp2  = (const float*)d_in[12];
    const float* bp2  = (const float*)d_in[13];
    float* out = (float*)d_out;

    char* ws = (char*)d_ws;
    size_t off = 0;
    auto alloc = [&](size_t bytes) -> void* {
        void* p = ws + off;
        off = (off + bytes + 255) & ~(size_t)255;
        return p;
    };
    const int N = N_NODES, E = N_EDGES, G = N_GRAPHS;
    u16* hA     = (u16*)alloc((size_t)N * EMB * 2);
    u16* hB     = (u16*)alloc((size_t)N * EMB * 2);
    u16* Wsw1   = (u16*)alloc(256 * 64 * 2);
    u16* Wsw2   = (u16*)alloc(256 * 256 * 2);
    u16* Wsw3   = (u16*)alloc(256 * 256 * 2);
    int* rowptr = (int*)alloc((size_t)(N + 1) * 4);
    int* deg    = (int*)alloc((size_t)N * 4);
    int* csr    = (int*)alloc((size_t)E * 4);
    int* partials = (int*)alloc(1024 * 4);
    int* gs     = (int*)alloc((size_t)(G + 1) * 4);

    if (off > ws_size) return;  // clean failure instead of OOB crash

    // CSR build (by dst)
    hipMemsetAsync(deg, 0, (size_t)N * 4, stream);
    count_deg<<<E / 256, 256, 0, stream>>>(dst, deg, E);
    scan_a<<<196, 256, 0, stream>>>(deg, rowptr + 1, partials, N);
    scan_b<<<1, 256, 0, stream>>>(partials, 196);
    scan_c<<<782, 256, 0, stream>>>(rowptr, partials, N);
    hipMemsetAsync(deg, 0, (size_t)N * 4, stream);  // reuse as cursor
    fill_csr<<<E / 256, 256, 0, stream>>>(src, dst, rowptr, deg, csr, E);

    // weight packing
    swizzle_wc<<<8, 256, 0, stream>>>(W1, W_emb, Wsw1);
    swizzle_w<<<32, 256, 0, stream>>>(W2, Wsw2);
    swizzle_w<<<32, 256, 0, stream>>>(W3, Wsw3);

    // layer 1 (fused): hA = relu(agg(x) @ Wc.T + b1)
    fused_gcn1<<<N / 16, 256, 0, stream>>>(x, rowptr, csr, Wsw1, b1, hA);
    // layer 2: hB = relu(agg(hA) @ W2.T + b2) + hA
    fused_gcn<<<N / 16, 256, 0, stream>>>(hA, rowptr, csr, Wsw2, b2, hB);
    // layer 3: hA = relu(agg(hB) @ W3.T + b3) + hB
    fused_gcn<<<N / 16, 256, 0, stream>>>(hB, rowptr, csr, Wsw3, b3, hA);

    // pooling + head
    graph_bounds<<<782, 256, 0, stream>>>(seg, gs, N, G);
    pool_head<<<G, 256, 0, stream>>>(hA, gs, Wp1, Wp2, bp2, out);
}

// Round 7
// 508.805 us; speedup vs baseline: 2.2381x; 1.0334x over previous
//
#include <hip/hip_runtime.h>
#include <hip/hip_bf16.h>

#define N_NODES 200000
#define N_EDGES 800000
#define N_GRAPHS 4000
#define D_N 35
#define IN_CH 8
#define EMB 256
#define HID 128

typedef unsigned short u16;
typedef __attribute__((ext_vector_type(8))) short bf16x8;
typedef __attribute__((ext_vector_type(8))) unsigned short ushort8;
typedef __attribute__((ext_vector_type(4))) float f32x4;

__device__ __forceinline__ float b2f(u16 u) {
    union { float f; unsigned v; } x; x.v = ((unsigned)u) << 16; return x.f;
}
__device__ __forceinline__ u16 f2b(float f) {
    union { float f; unsigned v; } x; x.f = f;
    unsigned r = x.v + 0x7fff + ((x.v >> 16) & 1);  // round-nearest-even
    return (u16)(r >> 16);
}
__device__ __forceinline__ int clampe(int e, int t) {
    int v = e < t ? e : (t - 1);
    return v < 0 ? 0 : v;
}
// accumulate 8 bf16 channels (as uint4) into float2[4]; lo u16 of each u32 = even ch
__device__ __forceinline__ void accum16(float2 (&ac)[4], uint4 v, bool p) {
    if (p) {
        unsigned uu[4] = {v.x, v.y, v.z, v.w};
#pragma unroll
        for (int j = 0; j < 4; j++) {
            union { unsigned u; float f; } lo, hi;
            lo.u = uu[j] << 16;
            hi.u = uu[j] & 0xffff0000u;
            ac[j].x += lo.f;
            ac[j].y += hi.f;
        }
    }
}

// ---------------- CSR build ----------------

__global__ void count_deg(const int* __restrict__ dst, int* __restrict__ deg, int n) {
    int e = blockIdx.x * 256 + threadIdx.x;
    if (e < n) atomicAdd(&deg[dst[e]], 1);
}

__global__ __launch_bounds__(256) void scan_a(const int* __restrict__ deg, int* __restrict__ incl1,
                                              int* __restrict__ partials, int n) {
    __shared__ int s[256];
    int tid = threadIdx.x;
    int base = blockIdx.x * 1024;
    int v[4]; int sum = 0;
#pragma unroll
    for (int j = 0; j < 4; j++) {
        int idx = base + tid * 4 + j;
        v[j] = (idx < n) ? deg[idx] : 0;
        sum += v[j];
    }
    s[tid] = sum; __syncthreads();
    for (int off = 1; off < 256; off <<= 1) {
        int t = (tid >= off) ? s[tid - off] : 0;
        __syncthreads();
        s[tid] += t;
        __syncthreads();
    }
    int run = s[tid] - sum;
#pragma unroll
    for (int j = 0; j < 4; j++) {
        int idx = base + tid * 4 + j;
        run += v[j];
        if (idx < n) incl1[idx] = run;
    }
    if (tid == 255) partials[blockIdx.x] = s[255];
}

__global__ __launch_bounds__(256) void scan_b(int* __restrict__ partials, int np) {
    __shared__ int s[256];
    int tid = threadIdx.x;
    int v = (tid < np) ? partials[tid] : 0;
    s[tid] = v; __syncthreads();
    for (int off = 1; off < 256; off <<= 1) {
        int t = (tid >= off) ? s[tid - off] : 0;
        __syncthreads();
        s[tid] += t;
        __syncthreads();
    }
    if (tid < np) partials[tid] = s[tid] - v;
}

__global__ void scan_c(int* __restrict__ rowptr, const int* __restrict__ partials, int n) {
    int i = blockIdx.x * 256 + threadIdx.x;
    if (i < n) rowptr[1 + i] += partials[i >> 10];
    if (i == 0) rowptr[0] = 0;
}

__global__ void fill_csr(const int* __restrict__ src, const int* __restrict__ dst,
                         const int* __restrict__ rowptr, int* __restrict__ cursor,
                         int* __restrict__ csr, int n) {
    int e = blockIdx.x * 256 + threadIdx.x;
    if (e >= n) return;
    int d = dst[e];
    int p = atomicAdd(&cursor[d], 1);
    csr[rowptr[d] + p] = src[e];
}

// ---------------- weight packing ----------------

// W [256 out][256 in] fp32 -> MFMA B-fragment order bf16
__global__ __launch_bounds__(256) void swizzle_w(const float* __restrict__ W, u16* __restrict__ Wsw) {
    int t = blockIdx.x * 256 + threadIdx.x;  // 8192 threads
    int lane = t & 63;
    int n = ((t >> 9) << 4) + (lane & 15);
    int k0 = (((t >> 6) & 7) << 5) + ((lane >> 4) << 3);
    u16 v[8];
#pragma unroll
    for (int j = 0; j < 8; j++) v[j] = f2b(W[(size_t)n * 256 + k0 + j]);
    ushort4* o = (ushort4*)&Wsw[(size_t)t * 8];
    o[0] = make_ushort4(v[0], v[1], v[2], v[3]);
    o[1] = make_ushort4(v[4], v[5], v[6], v[7]);
}

// Wc = W1[256,8] @ We[8,35], zero-padded to K=64, packed into B-fragment order.
__global__ __launch_bounds__(256) void swizzle_wc(const float* __restrict__ W1, const float* __restrict__ We,
                                                  u16* __restrict__ Wsw) {
    int t = blockIdx.x * 256 + threadIdx.x;  // 2048 threads
    int lane = t & 63;
    int nt = t >> 7;
    int ks = (t >> 6) & 1;
    int n = nt * 16 + (lane & 15);
    int k0 = ks * 32 + ((lane >> 4) << 3);
    float w1r[8];
#pragma unroll
    for (int i = 0; i < 8; i++) w1r[i] = W1[n * 8 + i];
    u16 v[8];
#pragma unroll
    for (int j = 0; j < 8; j++) {
        int k = k0 + j;
        float acc = 0.f;
        if (k < D_N) {
#pragma unroll
            for (int i = 0; i < 8; i++) acc += w1r[i] * We[i * D_N + k];
        }
        v[j] = f2b(acc);
    }
    ushort4* o = (ushort4*)&Wsw[(size_t)t * 8];
    o[0] = make_ushort4(v[0], v[1], v[2], v[3]);
    o[1] = make_ushort4(v[4], v[5], v[6], v[7]);
}

// ---------------- fused layer 1 ----------------
// Hout[r,:] = relu( (sum_{e: dst=r} x[src_e,:35]) @ Wc.T + b1 ), K padded to 64.
__global__ __launch_bounds__(256) void fused_gcn1(const float* __restrict__ x,
                                                  const int* __restrict__ rowptr,
                                                  const int* __restrict__ csr,
                                                  const u16* __restrict__ Wsw1,
                                                  const float* __restrict__ bias,
                                                  u16* __restrict__ Hout) {
    __shared__ __attribute__((aligned(16))) u16 lds[16][256];  // 8 KB
    const int wid = threadIdx.x >> 6;
    const int lane = threadIdx.x & 63;
    const int row0 = blockIdx.x * 16;
    char* ldsb = (char*)lds;

    // ---- phase 1: gather-sum x rows (fp32 exact), 8 edges in flight ----
    const int half = lane >> 5;
    const int cid = lane & 31;
    const int xe = (cid < 3) ? 32 + cid : 34;
    const int rbase = row0 + wid * 4;
    int4 rpa = *(const int4*)&rowptr[rbase];
    int rp4 = rowptr[rbase + 4];
    int e0 = rpa.x + half, e1 = rpa.y + half, e2 = rpa.z + half, e3 = rpa.w + half;
    const int t0 = rpa.y, t1 = rpa.z, t2 = rpa.w, t3 = rp4;
    int iA0 = csr[clampe(e0, t0)], iB0 = csr[clampe(e0 + 2, t0)];
    int iA1 = csr[clampe(e1, t1)], iB1 = csr[clampe(e1 + 2, t1)];
    int iA2 = csr[clampe(e2, t2)], iB2 = csr[clampe(e2 + 2, t2)];
    int iA3 = csr[clampe(e3, t3)], iB3 = csr[clampe(e3 + 2, t3)];
    bool pA0 = e0 < t0, pB0 = e0 + 2 < t0;
    bool pA1 = e1 < t1, pB1 = e1 + 2 < t1;
    bool pA2 = e2 < t2, pB2 = e2 + 2 < t2;
    bool pA3 = e3 < t3, pB3 = e3 + 2 < t3;
    float am0 = 0.f, am1 = 0.f, am2 = 0.f, am3 = 0.f;
    float ax0 = 0.f, ax1 = 0.f, ax2 = 0.f, ax3 = 0.f;
    while (__any((int)(pA0 | pA1 | pA2 | pA3 | pB0 | pB1 | pB2 | pB3))) {
        const float* qA0 = x + (size_t)iA0 * D_N;
        const float* qA1 = x + (size_t)iA1 * D_N;
        const float* qA2 = x + (size_t)iA2 * D_N;
        const float* qA3 = x + (size_t)iA3 * D_N;
        const float* qB0 = x + (size_t)iB0 * D_N;
        const float* qB1 = x + (size_t)iB1 * D_N;
        const float* qB2 = x + (size_t)iB2 * D_N;
        const float* qB3 = x + (size_t)iB3 * D_N;
        float vA0 = qA0[cid], wA0 = qA0[xe];
        float vA1 = qA1[cid], wA1 = qA1[xe];
        float vA2 = qA2[cid], wA2 = qA2[xe];
        float vA3 = qA3[cid], wA3 = qA3[xe];
        float vB0 = qB0[cid], wB0 = qB0[xe];
        float vB1 = qB1[cid], wB1 = qB1[xe];
        float vB2 = qB2[cid], wB2 = qB2[xe];
        float vB3 = qB3[cid], wB3 = qB3[xe];
        e0 += 4; e1 += 4; e2 += 4; e3 += 4;
        int jA0 = csr[clampe(e0, t0)], jB0 = csr[clampe(e0 + 2, t0)];
        int jA1 = csr[clampe(e1, t1)], jB1 = csr[clampe(e1 + 2, t1)];
        int jA2 = csr[clampe(e2, t2)], jB2 = csr[clampe(e2 + 2, t2)];
        int jA3 = csr[clampe(e3, t3)], jB3 = csr[clampe(e3 + 2, t3)];
        if (pA0) { am0 += vA0; ax0 += wA0; }
        if (pB0) { am0 += vB0; ax0 += wB0; }
        if (pA1) { am1 += vA1; ax1 += wA1; }
        if (pB1) { am1 += vB1; ax1 += wB1; }
        if (pA2) { am2 += vA2; ax2 += wA2; }
        if (pB2) { am2 += vB2; ax2 += wB2; }
        if (pA3) { am3 += vA3; ax3 += wA3; }
        if (pB3) { am3 += vB3; ax3 += wB3; }
        iA0 = jA0; iB0 = jB0; iA1 = jA1; iB1 = jB1;
        iA2 = jA2; iB2 = jB2; iA3 = jA3; iB3 = jB3;
        pA0 = e0 < t0; pB0 = e0 + 2 < t0;
        pA1 = e1 < t1; pB1 = e1 + 2 < t1;
        pA2 = e2 < t2; pB2 = e2 + 2 < t2;
        pA3 = e3 < t3; pB3 = e3 + 2 < t3;
    }
    am0 += __shfl_xor(am0, 32, 64); ax0 += __shfl_xor(ax0, 32, 64);
    am1 += __shfl_xor(am1, 32, 64); ax1 += __shfl_xor(ax1, 32, 64);
    am2 += __shfl_xor(am2, 32, 64); ax2 += __shfl_xor(ax2, 32, 64);
    am3 += __shfl_xor(am3, 32, 64); ax3 += __shfl_xor(ax3, 32, 64);
    if (half == 0) {
        float ams[4] = {am0, am1, am2, am3};
        float axs[4] = {ax0, ax1, ax2, ax3};
#pragma unroll
        for (int j = 0; j < 4; j++) {
            int li = wid * 4 + j;
            int sw = (li & 7) << 4;
            *(u16*)(ldsb + li * 128 + ((cid * 2) ^ sw)) = f2b(ams[j]);
            u16 zv = (cid < 3) ? f2b(axs[j]) : (u16)0;
            *(u16*)(ldsb + li * 128 + (((32 + cid) * 2) ^ sw)) = zv;
        }
    }
    __syncthreads();

    // ---- phase 2: A fragments (K=64 tile, stride 128B, swizzled) ----
    const int m = lane & 15;
    const int g = lane >> 4;
    bf16x8 a[2];
#pragma unroll
    for (int ks = 0; ks < 2; ks++) {
        int boff = (ks * 64 + g * 16) ^ ((m & 7) << 4);
        a[ks] = *(const bf16x8*)(ldsb + m * 128 + boff);
    }
    __syncthreads();

    // ---- phase 3: MFMA ----
    f32x4 acc[4];
#pragma unroll
    for (int t = 0; t < 4; t++) acc[t] = (f32x4){0.f, 0.f, 0.f, 0.f};
    const bf16x8* wp = (const bf16x8*)Wsw1 + lane;
#pragma unroll
    for (int t = 0; t < 4; t++) {
        int nt = wid * 4 + t;
        bf16x8 b0 = wp[(nt * 2 + 0) * 64];
        bf16x8 b1 = wp[(nt * 2 + 1) * 64];
        acc[t] = __builtin_amdgcn_mfma_f32_16x16x32_bf16(a[0], b0, acc[t], 0, 0, 0);
        acc[t] = __builtin_amdgcn_mfma_f32_16x16x32_bf16(a[1], b1, acc[t], 0, 0, 0);
    }

    // ---- phase 4: C -> LDS ----
#pragma unroll
    for (int t = 0; t < 4; t++) {
        int col = (wid * 4 + t) * 16 + m;
#pragma unroll
        for (int r = 0; r < 4; r++) {
            int row = g * 4 + r;
            *(u16*)(ldsb + row * 512 + ((col * 2) ^ ((row & 7) << 4))) = f2b(acc[t][r]);
        }
    }
    __syncthreads();

    // ---- phase 5: epilogue relu + bias ----
    {
        int row = threadIdx.x >> 4;
        int cb0 = (threadIdx.x & 15) * 16;
#pragma unroll
        for (int p = 0; p < 2; p++) {
            int cb = cb0 + p * 256;
            ushort8 c = *(const ushort8*)(ldsb + row * 512 + (cb ^ ((row & 7) << 4)));
            int gcol = cb >> 1;
            size_t gidx = (size_t)(row0 + row) * EMB + gcol;
            float4 bq0 = *(const float4*)&bias[gcol];
            float4 bq1 = *(const float4*)&bias[gcol + 4];
            float bb[8] = {bq0.x, bq0.y, bq0.z, bq0.w, bq1.x, bq1.y, bq1.z, bq1.w};
            ushort8 o;
#pragma unroll
            for (int j = 0; j < 8; j++)
                o[j] = f2b(fmaxf(b2f(c[j]) + bb[j], 0.f));
            *(ushort8*)&Hout[gidx] = o;
        }
    }
}

// ---------------- fused GCN layer (2,3) ----------------
// Hout[r,:] = relu( (sum_{e: dst=r} Hin[src_e,:]) @ W.T + bias ) + Hin[r,:]
__global__ __launch_bounds__(256) void fused_gcn(const u16* __restrict__ Hin,
                                                 const int* __restrict__ rowptr,
                                                 const int* __restrict__ csr,
                                                 const u16* __restrict__ Wsw,
                                                 const float* __restrict__ bias,
                                                 u16* __restrict__ Hout) {
    __shared__ __attribute__((aligned(16))) u16 lds[16][256];  // 8 KB
    const int wid = threadIdx.x >> 6;
    const int lane = threadIdx.x & 63;
    const int row0 = blockIdx.x * 16;
    char* ldsb = (char*)lds;
    const char* hbase = (const char*)Hin;

    // ---- phase 1: gather, 8 edges (4 rows x 2) in flight, csr one iter ahead ----
    const int half = lane >> 5;
    const int c8b = (lane & 31) * 16;
    const int rbase = row0 + wid * 4;
    int4 rpa = *(const int4*)&rowptr[rbase];
    int rp4 = rowptr[rbase + 4];
    int e0 = rpa.x + half, e1 = rpa.y + half, e2 = rpa.z + half, e3 = rpa.w + half;
    const int t0 = rpa.y, t1 = rpa.z, t2 = rpa.w, t3 = rp4;
    int iA0 = csr[clampe(e0, t0)], iB0 = csr[clampe(e0 + 2, t0)];
    int iA1 = csr[clampe(e1, t1)], iB1 = csr[clampe(e1 + 2, t1)];
    int iA2 = csr[clampe(e2, t2)], iB2 = csr[clampe(e2 + 2, t2)];
    int iA3 = csr[clampe(e3, t3)], iB3 = csr[clampe(e3 + 2, t3)];
    bool pA0 = e0 < t0, pB0 = e0 + 2 < t0;
    bool pA1 = e1 < t1, pB1 = e1 + 2 < t1;
    bool pA2 = e2 < t2, pB2 = e2 + 2 < t2;
    bool pA3 = e3 < t3, pB3 = e3 + 2 < t3;
    float2 ac0[4], ac1[4], ac2[4], ac3[4];
#pragma unroll
    for (int j = 0; j < 4; j++) {
        ac0[j] = make_float2(0.f, 0.f); ac1[j] = make_float2(0.f, 0.f);
        ac2[j] = make_float2(0.f, 0.f); ac3[j] = make_float2(0.f, 0.f);
    }
    while (__any((int)(pA0 | pA1 | pA2 | pA3 | pB0 | pB1 | pB2 | pB3))) {
        uint4 vA0 = *(const uint4*)(hbase + (size_t)iA0 * (EMB * 2) + c8b);
        uint4 vA1 = *(const uint4*)(hbase + (size_t)iA1 * (EMB * 2) + c8b);
        uint4 vA2 = *(const uint4*)(hbase + (size_t)iA2 * (EMB * 2) + c8b);
        uint4 vA3 = *(const uint4*)(hbase + (size_t)iA3 * (EMB * 2) + c8b);
        uint4 vB0 = *(const uint4*)(hbase + (size_t)iB0 * (EMB * 2) + c8b);
        uint4 vB1 = *(const uint4*)(hbase + (size_t)iB1 * (EMB * 2) + c8b);
        uint4 vB2 = *(const uint4*)(hbase + (size_t)iB2 * (EMB * 2) + c8b);
        uint4 vB3 = *(const uint4*)(hbase + (size_t)iB3 * (EMB * 2) + c8b);
        e0 += 4; e1 += 4; e2 += 4; e3 += 4;
        int jA0 = csr[clampe(e0, t0)], jB0 = csr[clampe(e0 + 2, t0)];
        int jA1 = csr[clampe(e1, t1)], jB1 = csr[clampe(e1 + 2, t1)];
        int jA2 = csr[clampe(e2, t2)], jB2 = csr[clampe(e2 + 2, t2)];
        int jA3 = csr[clampe(e3, t3)], jB3 = csr[clampe(e3 + 2, t3)];
        accum16(ac0, vA0, pA0); accum16(ac0, vB0, pB0);
        accum16(ac1, vA1, pA1); accum16(ac1, vB1, pB1);
        accum16(ac2, vA2, pA2); accum16(ac2, vB2, pB2);
        accum16(ac3, vA3, pA3); accum16(ac3, vB3, pB3);
        iA0 = jA0; iB0 = jB0; iA1 = jA1; iB1 = jB1;
        iA2 = jA2; iB2 = jB2; iA3 = jA3; iB3 = jB3;
        pA0 = e0 < t0; pB0 = e0 + 2 < t0;
        pA1 = e1 < t1; pB1 = e1 + 2 < t1;
        pA2 = e2 < t2; pB2 = e2 + 2 < t2;
        pA3 = e3 < t3; pB3 = e3 + 2 < t3;
    }
#pragma unroll
    for (int j = 0; j < 4; j++) {
        ac0[j].x += __shfl_xor(ac0[j].x, 32, 64); ac0[j].y += __shfl_xor(ac0[j].y, 32, 64);
        ac1[j].x += __shfl_xor(ac1[j].x, 32, 64); ac1[j].y += __shfl_xor(ac1[j].y, 32, 64);
        ac2[j].x += __shfl_xor(ac2[j].x, 32, 64); ac2[j].y += __shfl_xor(ac2[j].y, 32, 64);
        ac3[j].x += __shfl_xor(ac3[j].x, 32, 64); ac3[j].y += __shfl_xor(ac3[j].y, 32, 64);
    }
    if (half == 0) {
        ushort8 o0, o1, o2, o3;
#pragma unroll
        for (int j = 0; j < 4; j++) {
            o0[2 * j] = f2b(ac0[j].x); o0[2 * j + 1] = f2b(ac0[j].y);
            o1[2 * j] = f2b(ac1[j].x); o1[2 * j + 1] = f2b(ac1[j].y);
            o2[2 * j] = f2b(ac2[j].x); o2[2 * j + 1] = f2b(ac2[j].y);
            o3[2 * j] = f2b(ac3[j].x); o3[2 * j + 1] = f2b(ac3[j].y);
        }
        int li = wid * 4;
        *(ushort8*)(ldsb + (li + 0) * 512 + (c8b ^ (((li + 0) & 7) << 4))) = o0;
        *(ushort8*)(ldsb + (li + 1) * 512 + (c8b ^ (((li + 1) & 7) << 4))) = o1;
        *(ushort8*)(ldsb + (li + 2) * 512 + (c8b ^ (((li + 2) & 7) << 4))) = o2;
        *(ushort8*)(ldsb + (li + 3) * 512 + (c8b ^ (((li + 3) & 7) << 4))) = o3;
    }

    // residual prefetch: issue now, consumed in phase 5 (2 barriers + MFMA of cover)
    const int rrow = threadIdx.x >> 4;
    const int rcb = (threadIdx.x & 15) * 16;
    ushort8 res0 = *(const ushort8*)(hbase + (size_t)(row0 + rrow) * 512 + rcb);
    ushort8 res1 = *(const ushort8*)(hbase + (size_t)(row0 + rrow) * 512 + rcb + 256);
    __syncthreads();

    // ---- phase 2: A fragments ----
    const int m = lane & 15;
    const int g = lane >> 4;
    bf16x8 a[8];
#pragma unroll
    for (int ks = 0; ks < 8; ks++) {
        int boff = (g * 16 + ks * 64) ^ ((m & 7) << 4);
        a[ks] = *(const bf16x8*)(ldsb + m * 512 + boff);
    }
    __syncthreads();

    // ---- phase 3: MFMA, wave owns col-tiles wid*4..wid*4+3 ----
    f32x4 acc[4];
#pragma unroll
    for (int t = 0; t < 4; t++) acc[t] = (f32x4){0.f, 0.f, 0.f, 0.f};
    const bf16x8* wp = (const bf16x8*)Wsw + lane;
#pragma unroll
    for (int t = 0; t < 4; t++) {
        int nt = wid * 4 + t;
        bf16x8 b[8];
#pragma unroll
        for (int ks = 0; ks < 8; ks++) b[ks] = wp[(nt * 8 + ks) * 64];
#pragma unroll
        for (int ks = 0; ks < 8; ks++)
            acc[t] = __builtin_amdgcn_mfma_f32_16x16x32_bf16(a[ks], b[ks], acc[t], 0, 0, 0);
    }

    // ---- phase 4: C -> LDS (bf16, swizzled) ----
#pragma unroll
    for (int t = 0; t < 4; t++) {
        int col = (wid * 4 + t) * 16 + m;
#pragma unroll
        for (int r = 0; r < 4; r++) {
            int row = g * 4 + r;
            *(u16*)(ldsb + row * 512 + ((col * 2) ^ ((row & 7) << 4))) = f2b(acc[t][r]);
        }
    }
    __syncthreads();

    // ---- phase 5: epilogue relu + bias + prefetched residual ----
    {
        int row = rrow;
        int cb0 = rcb;
        ushort8 resv[2] = {res0, res1};
#pragma unroll
        for (int p = 0; p < 2; p++) {
            int cb = cb0 + p * 256;
            ushort8 c = *(const ushort8*)(ldsb + row * 512 + (cb ^ ((row & 7) << 4)));
            int gcol = cb >> 1;
            size_t gidx = (size_t)(row0 + row) * EMB + gcol;
            float4 bq0 = *(const float4*)&bias[gcol];
            float4 bq1 = *(const float4*)&bias[gcol + 4];
            float bb[8] = {bq0.x, bq0.y, bq0.z, bq0.w, bq1.x, bq1.y, bq1.z, bq1.w};
            ushort8 o;
#pragma unroll
            for (int j = 0; j < 8; j++)
                o[j] = f2b(fmaxf(b2f(c[j]) + bb[j], 0.f) + b2f(resv[p][j]));
            *(ushort8*)&Hout[gidx] = o;
        }
    }
}

// ---------------- pooling + head (fused) ----------------

__global__ void graph_bounds(const int* __restrict__ seg, int* __restrict__ gs, int n, int B) {
    int i = blockIdx.x * 256 + threadIdx.x;
    if (i >= n) return;
    int c = seg[i];
    int p = (i == 0) ? -1 : seg[i - 1];
    for (int b = p + 1; b <= c; b++) gs[b] = i;
    if (i == n - 1) {
        for (int b = c + 1; b <= B; b++) gs[b] = n;
    }
}

__global__ __launch_bounds__(256) void pool_head(const u16* __restrict__ h, const int* __restrict__ gs,
                                                 const float* __restrict__ Wp1, const float* __restrict__ Wp2,
                                                 const float* __restrict__ bp2, float* __restrict__ out) {
    __shared__ float gpq[4][EMB];
    __shared__ float gp[EMB];
    __shared__ float red[HID];
    int b = blockIdx.x, t = threadIdx.x;
    int s = gs[b], e = gs[b + 1];
    int q = t >> 6, ch4 = (t & 63) * 4;
    float a0 = 0.f, a1 = 0.f, a2 = 0.f, a3 = 0.f;
    int r = s + q;
    for (; r + 4 < e; r += 8) {
        ushort4 va = *(const ushort4*)&h[(size_t)r * EMB + ch4];
        ushort4 vb = *(const ushort4*)&h[(size_t)(r + 4) * EMB + ch4];
        a0 += b2f(va.x) + b2f(vb.x);
        a1 += b2f(va.y) + b2f(vb.y);
        a2 += b2f(va.z) + b2f(vb.z);
        a3 += b2f(va.w) + b2f(vb.w);
    }
    if (r < e) {
        ushort4 va = *(const ushort4*)&h[(size_t)r * EMB + ch4];
        a0 += b2f(va.x); a1 += b2f(va.y); a2 += b2f(va.z); a3 += b2f(va.w);
    }
    *(float4*)&gpq[q][ch4] = make_float4(a0, a1, a2, a3);
    __syncthreads();
    gp[t] = gpq[0][t] + gpq[1][t] + gpq[2][t] + gpq[3][t];
    __syncthreads();
    if (t < HID) {
        float acc = 0.f;
        const float4* wr = (const float4*)&Wp1[(size_t)t * EMB];
        const float4* gp4 = (const float4*)gp;
#pragma unroll 8
        for (int k = 0; k < EMB / 4; k++) {
            float4 w = wr[k], gg = gp4[k];
            acc += w.x * gg.x + w.y * gg.y + w.z * gg.z + w.w * gg.w;
        }
        red[t] = fmaxf(acc, 0.f) * Wp2[t];
    }
    __syncthreads();
    for (int off = 64; off > 0; off >>= 1) {
        if (t < off) red[t] += red[t + off];
        __syncthreads();
    }
    if (t == 0) out[b] = red[0] + bp2[0];
}

// ---------------- launch ----------------

extern "C" void kernel_launch(void* const* d_in, const int* in_sizes, int n_in,
                              void* d_out, int out_size, void* d_ws, size_t ws_size,
                              hipStream_t stream) {
    const float* x    = (const float*)d_in[0];
    const int*   src  = (const int*)d_in[1];
    const int*   dst  = (const int*)d_in[2];
    const int*   seg  = (const int*)d_in[3];
    const float* W_emb= (const float*)d_in[4];
    const float* W1   = (const float*)d_in[5];
    const float* b1   = (const float*)d_in[6];
    const float* W2   = (const float*)d_in[7];
    const float* b2   = (const float*)d_in[8];
    const float* W3   = (const float*)d_in[9];
    const float* b3   = (const float*)d_in[10];
    const float* Wp1  = (const float*)d_in[11];
    const float* Wp2  = (const float*)d_in[12];
    const float* bp2  = (const float*)d_in[13];
    float* out = (float*)d_out;

    char* ws = (char*)d_ws;
    size_t off = 0;
    auto alloc = [&](size_t bytes) -> void* {
        void* p = ws + off;
        off = (off + bytes + 255) & ~(size_t)255;
        return p;
    };
    const int N = N_NODES, E = N_EDGES, G = N_GRAPHS;
    u16* hA     = (u16*)alloc((size_t)N * EMB * 2);
    u16* hB     = (u16*)alloc((size_t)N * EMB * 2);
    u16* Wsw1   = (u16*)alloc(256 * 64 * 2);
    u16* Wsw2   = (u16*)alloc(256 * 256 * 2);
    u16* Wsw3   = (u16*)alloc(256 * 256 * 2);
    int* rowptr = (int*)alloc((size_t)(N + 1) * 4);
    int* deg    = (int*)alloc((size_t)N * 4);
    int* csr    = (int*)alloc((size_t)E * 4);
    int* partials = (int*)alloc(1024 * 4);
    int* gs     = (int*)alloc((size_t)(G + 1) * 4);

    if (off > ws_size) return;  // clean failure instead of OOB crash

    // CSR build (by dst)
    hipMemsetAsync(deg, 0, (size_t)N * 4, stream);
    count_deg<<<E / 256, 256, 0, stream>>>(dst, deg, E);
    scan_a<<<196, 256, 0, stream>>>(deg, rowptr + 1, partials, N);
    scan_b<<<1, 256, 0, stream>>>(partials, 196);
    scan_c<<<782, 256, 0, stream>>>(rowptr, partials, N);
    hipMemsetAsync(deg, 0, (size_t)N * 4, stream);  // reuse as cursor
    fill_csr<<<E / 256, 256, 0, stream>>>(src, dst, rowptr, deg, csr, E);

    // weight packing
    swizzle_wc<<<8, 256, 0, stream>>>(W1, W_emb, Wsw1);
    swizzle_w<<<32, 256, 0, stream>>>(W2, Wsw2);
    swizzle_w<<<32, 256, 0, stream>>>(W3, Wsw3);

    // layer 1 (fused): hA = relu(agg(x) @ Wc.T + b1)
    fused_gcn1<<<N / 16, 256, 0, stream>>>(x, rowptr, csr, Wsw1, b1, hA);
    // layer 2: hB = relu(agg(hA) @ W2.T + b2) + hA
    fused_gcn<<<N / 16, 256, 0, stream>>>(hA, rowptr, csr, Wsw2, b2, hB);
    // layer 3: hA = relu(agg(hB) @ W3.T + b3) + hB
    fused_gcn<<<N / 16, 256, 0, stream>>>(hB, rowptr, csr, Wsw3, b3, hA);

    // pooling + head
    graph_bounds<<<782, 256, 0, stream>>>(seg, gs, N, G);
    pool_head<<<G, 256, 0, stream>>>(hA, gs, Wp1, Wp2, bp2, out);
}

// Round 8
// 459.506 us; speedup vs baseline: 2.4782x; 1.1073x over previous
//
#include <hip/hip_runtime.h>
#include <hip/hip_bf16.h>

#define N_NODES 200000
#define N_EDGES 800000
#define N_GRAPHS 4000
#define D_N 35
#define IN_CH 8
#define EMB 256
#define HID 128

typedef unsigned short u16;
typedef __attribute__((ext_vector_type(8))) short bf16x8;
typedef __attribute__((ext_vector_type(8))) unsigned short ushort8;
typedef __attribute__((ext_vector_type(4))) float f32x4;

__device__ __forceinline__ float b2f(u16 u) {
    union { float f; unsigned v; } x; x.v = ((unsigned)u) << 16; return x.f;
}
__device__ __forceinline__ u16 f2b(float f) {
    union { float f; unsigned v; } x; x.f = f;
    unsigned r = x.v + 0x7fff + ((x.v >> 16) & 1);  // round-nearest-even
    return (u16)(r >> 16);
}
#define RFL(v) __builtin_amdgcn_readfirstlane(v)

// ---------------- CSR build ----------------

__global__ void count_deg(const int* __restrict__ dst, int* __restrict__ deg, int n) {
    int e = blockIdx.x * 256 + threadIdx.x;
    if (e < n) atomicAdd(&deg[dst[e]], 1);
}

__global__ __launch_bounds__(256) void scan_a(const int* __restrict__ deg, int* __restrict__ incl1,
                                              int* __restrict__ partials, int n) {
    __shared__ int s[256];
    int tid = threadIdx.x;
    int base = blockIdx.x * 1024;
    int v[4]; int sum = 0;
#pragma unroll
    for (int j = 0; j < 4; j++) {
        int idx = base + tid * 4 + j;
        v[j] = (idx < n) ? deg[idx] : 0;
        sum += v[j];
    }
    s[tid] = sum; __syncthreads();
    for (int off = 1; off < 256; off <<= 1) {
        int t = (tid >= off) ? s[tid - off] : 0;
        __syncthreads();
        s[tid] += t;
        __syncthreads();
    }
    int run = s[tid] - sum;
#pragma unroll
    for (int j = 0; j < 4; j++) {
        int idx = base + tid * 4 + j;
        run += v[j];
        if (idx < n) incl1[idx] = run;
    }
    if (tid == 255) partials[blockIdx.x] = s[255];
}

__global__ __launch_bounds__(256) void scan_b(int* __restrict__ partials, int np) {
    __shared__ int s[256];
    int tid = threadIdx.x;
    int v = (tid < np) ? partials[tid] : 0;
    s[tid] = v; __syncthreads();
    for (int off = 1; off < 256; off <<= 1) {
        int t = (tid >= off) ? s[tid - off] : 0;
        __syncthreads();
        s[tid] += t;
        __syncthreads();
    }
    if (tid < np) partials[tid] = s[tid] - v;
}

__global__ void scan_c(int* __restrict__ rowptr, const int* __restrict__ partials, int n) {
    int i = blockIdx.x * 256 + threadIdx.x;
    if (i < n) rowptr[1 + i] += partials[i >> 10];
    if (i == 0) rowptr[0] = 0;
}

__global__ void fill_csr(const int* __restrict__ src, const int* __restrict__ dst,
                         const int* __restrict__ rowptr, int* __restrict__ cursor,
                         int* __restrict__ csr, int n) {
    int e = blockIdx.x * 256 + threadIdx.x;
    if (e >= n) return;
    int d = dst[e];
    int p = atomicAdd(&cursor[d], 1);
    csr[rowptr[d] + p] = src[e];
}

// ---------------- weight packing ----------------

// W [256 out][256 in] fp32 -> MFMA B-fragment order bf16
__global__ __launch_bounds__(256) void swizzle_w(const float* __restrict__ W, u16* __restrict__ Wsw) {
    int t = blockIdx.x * 256 + threadIdx.x;  // 8192 threads
    int lane = t & 63;
    int n = ((t >> 9) << 4) + (lane & 15);
    int k0 = (((t >> 6) & 7) << 5) + ((lane >> 4) << 3);
    u16 v[8];
#pragma unroll
    for (int j = 0; j < 8; j++) v[j] = f2b(W[(size_t)n * 256 + k0 + j]);
    ushort4* o = (ushort4*)&Wsw[(size_t)t * 8];
    o[0] = make_ushort4(v[0], v[1], v[2], v[3]);
    o[1] = make_ushort4(v[4], v[5], v[6], v[7]);
}

// W1 [256 out][8 in] -> B-fragment order for one 16x16x32 MFMA (k 8..31 zero)
__global__ __launch_bounds__(256) void swizzle_w1(const float* __restrict__ W1, u16* __restrict__ Wsw) {
    int t = blockIdx.x * 256 + threadIdx.x;  // 1024 threads: nt(16) x lane(64)
    int lane = t & 63;
    int nt = t >> 6;
    int n = nt * 16 + (lane & 15);
    int g = lane >> 4;
    u16 v[8];
#pragma unroll
    for (int j = 0; j < 8; j++) v[j] = (g == 0) ? f2b(W1[n * 8 + j]) : (u16)0;
    ushort4* o = (ushort4*)&Wsw[(size_t)t * 8];
    o[0] = make_ushort4(v[0], v[1], v[2], v[3]);
    o[1] = make_ushort4(v[4], v[5], v[6], v[7]);
}

// ---------------- emb: h0 = bf16(x @ We.T)  [N,8] ----------------
__global__ __launch_bounds__(256) void emb8(const float* __restrict__ x, const float* __restrict__ We,
                                            u16* __restrict__ h0, int n) {
    __shared__ float ws[IN_CH * D_N];
    int tid = threadIdx.x;
    for (int i = tid; i < IN_CH * D_N; i += 256) ws[i] = We[i];
    __syncthreads();
    int node = blockIdx.x * 256 + tid;
    if (node >= n) return;
    float xr[D_N];
    const float* xp = &x[(size_t)node * D_N];
#pragma unroll
    for (int k = 0; k < D_N; k++) xr[k] = xp[k];
    ushort8 o;
#pragma unroll
    for (int j = 0; j < IN_CH; j++) {
        float acc = 0.f;
#pragma unroll
        for (int k = 0; k < D_N; k++) acc += xr[k] * ws[j * D_N + k];
        o[j] = f2b(acc);
    }
    *(ushort8*)&h0[(size_t)node * IN_CH] = o;
}

// ---------------- fused layer 1: agg8 + MFMA GEMM (8->256) ----------------
// Hout[r,:] = relu( (sum_{e: dst=r} h0[src_e,:]) @ W1.T + b1 )
__global__ __launch_bounds__(256) void fused_l1(const u16* __restrict__ h0,
                                                const int* __restrict__ rowptr,
                                                const int* __restrict__ csr,
                                                const u16* __restrict__ Wsw1,
                                                const float* __restrict__ bias,
                                                u16* __restrict__ Hout) {
    __shared__ __attribute__((aligned(16))) u16 lds[16][256];  // 8 KB; agg uses [16][8] front
    const int wid = threadIdx.x >> 6;
    const int lane = threadIdx.x & 63;
    const int row0 = blockIdx.x * 16;
    char* ldsb = (char*)lds;
    const char* h0c = (const char*)h0;

    // ---- phase 1: each wave aggregates rows rbase..rbase+3 (16 edges/iter/row) ----
    const int slot = lane >> 2;          // edge slot 0..15
    const int cid2 = (lane & 3) * 4;     // byte offset of this lane's 2 channels
    const int rbase = row0 + wid * 4;
    int s0 = RFL(rowptr[rbase + 0]);
    int s1 = RFL(rowptr[rbase + 1]);
    int s2 = RFL(rowptr[rbase + 2]);
    int s3 = RFL(rowptr[rbase + 3]);
    int s4 = RFL(rowptr[rbase + 4]);
    int es[5] = {s0, s1, s2, s3, s4};
#pragma unroll
    for (int r = 0; r < 4; r++) {
        int er = es[r], tr = es[r + 1];
        float2 acc = make_float2(0.f, 0.f);
        for (int eb = er; eb < tr; eb += 16) {
            int e = eb + slot;
            int ce = e < tr ? e : tr - 1;
            int sidx = csr[ce];
            unsigned v = *(const unsigned*)(h0c + (size_t)sidx * 16 + cid2);
            if (e < tr) {
                union { unsigned u; float f; } lo, hi;
                lo.u = v << 16; hi.u = v & 0xffff0000u;
                acc.x += lo.f; acc.y += hi.f;
            }
        }
        acc.x += __shfl_xor(acc.x, 4, 64);  acc.y += __shfl_xor(acc.y, 4, 64);
        acc.x += __shfl_xor(acc.x, 8, 64);  acc.y += __shfl_xor(acc.y, 8, 64);
        acc.x += __shfl_xor(acc.x, 16, 64); acc.y += __shfl_xor(acc.y, 16, 64);
        acc.x += __shfl_xor(acc.x, 32, 64); acc.y += __shfl_xor(acc.y, 32, 64);
        if (lane < 4) {
            unsigned pk = (unsigned)f2b(acc.x) | ((unsigned)f2b(acc.y) << 16);
            *(unsigned*)(ldsb + (wid * 4 + r) * 16 + cid2) = pk;
        }
    }
    __syncthreads();

    // ---- phase 2: A fragment (K=32: k<8 real, rest zero) ----
    const int m = lane & 15;
    const int g = lane >> 4;
    bf16x8 a = {};
    if (g == 0) a = *(const bf16x8*)(ldsb + m * 16);
    __syncthreads();

    // ---- phase 3: 1 MFMA per col-tile, wave owns col-tiles wid*4..wid*4+3 ----
    f32x4 acc[4];
#pragma unroll
    for (int t = 0; t < 4; t++) acc[t] = (f32x4){0.f, 0.f, 0.f, 0.f};
    const bf16x8* wp = (const bf16x8*)Wsw1 + lane;
#pragma unroll
    for (int t = 0; t < 4; t++) {
        bf16x8 b = wp[(wid * 4 + t) * 64];
        acc[t] = __builtin_amdgcn_mfma_f32_16x16x32_bf16(a, b, acc[t], 0, 0, 0);
    }

    // ---- phase 4: C -> LDS (bf16, swizzled [16][512B]) ----
#pragma unroll
    for (int t = 0; t < 4; t++) {
        int col = (wid * 4 + t) * 16 + m;
#pragma unroll
        for (int r = 0; r < 4; r++) {
            int row = g * 4 + r;
            *(u16*)(ldsb + row * 512 + ((col * 2) ^ ((row & 7) << 4))) = f2b(acc[t][r]);
        }
    }
    __syncthreads();

    // ---- phase 5: epilogue relu + bias ----
    {
        int row = threadIdx.x >> 4;
        int cb0 = (threadIdx.x & 15) * 16;
#pragma unroll
        for (int p = 0; p < 2; p++) {
            int cb = cb0 + p * 256;
            ushort8 c = *(const ushort8*)(ldsb + row * 512 + (cb ^ ((row & 7) << 4)));
            int gcol = cb >> 1;
            size_t gidx = (size_t)(row0 + row) * EMB + gcol;
            float4 bq0 = *(const float4*)&bias[gcol];
            float4 bq1 = *(const float4*)&bias[gcol + 4];
            float bb[8] = {bq0.x, bq0.y, bq0.z, bq0.w, bq1.x, bq1.y, bq1.z, bq1.w};
            ushort8 o;
#pragma unroll
            for (int j = 0; j < 8; j++)
                o[j] = f2b(fmaxf(b2f(c[j]) + bb[j], 0.f));
            *(ushort8*)&Hout[gidx] = o;
        }
    }
}

// ---------------- fused GCN layer (2,3) ----------------
// Hout[r,:] = relu( (sum_{e: dst=r} Hin[src_e,:]) @ W.T + bias ) + Hin[r,:]
// Scalarized gather: rowptr/csr/predicates in SGPRs, full-wave uint2 row reads
// (lane covers ch 4l..4l+3), 4 rows x depth 4 = 16 edges in flight.
__global__ __launch_bounds__(256, 8) void fused_gcn(const u16* __restrict__ Hin,
                                                    const int* __restrict__ rowptr,
                                                    const int* __restrict__ csr,
                                                    const u16* __restrict__ Wsw,
                                                    const float* __restrict__ bias,
                                                    u16* __restrict__ Hout) {
    __shared__ __attribute__((aligned(16))) u16 lds[16][256];  // 8 KB
    const int wid = threadIdx.x >> 6;
    const int lane = threadIdx.x & 63;
    const int row0 = blockIdx.x * 16;
    char* ldsb = (char*)lds;
    const char* hbase = (const char*)Hin;
    const int laneByte = lane * 8;

    // ---- phase 1: gather (wave-uniform control in SGPRs) ----
    const int rbase = row0 + wid * 4;
    int e0 = RFL(rowptr[rbase + 0]);
    int t0 = RFL(rowptr[rbase + 1]);
    int t1 = RFL(rowptr[rbase + 2]);
    int t2 = RFL(rowptr[rbase + 3]);
    int t3 = RFL(rowptr[rbase + 4]);
    int e1 = t0, e2 = t1, e3 = t2;

    float2 acc[4][2];
#pragma unroll
    for (int r = 0; r < 4; r++) {
        acc[r][0] = make_float2(0.f, 0.f);
        acc[r][1] = make_float2(0.f, 0.f);
    }

    int ee[4] = {e0, e1, e2, e3};
    int tt[4] = {t0, t1, t2, t3};
    int idx[4][4];
#pragma unroll
    for (int r = 0; r < 4; r++) {
#pragma unroll
        for (int d = 0; d < 4; d++) {
            int ce = ee[r] + d;
            if (ce >= tt[r]) ce = tt[r] - 1;
            if (ce < 0) ce = 0;
            idx[r][d] = RFL(csr[ce]);
        }
    }

    while ((ee[0] < tt[0]) | (ee[1] < tt[1]) | (ee[2] < tt[2]) | (ee[3] < tt[3])) {
        // issue all 16 loads (clamped indices; duplicates are cache hits)
        uint2 val[4][4];
#pragma unroll
        for (int r = 0; r < 4; r++)
#pragma unroll
            for (int d = 0; d < 4; d++)
                val[r][d] = *(const uint2*)(hbase + (size_t)idx[r][d] * (EMB * 2) + laneByte);
        // save predicates, advance, prefetch next indices
        bool pr[4][4];
#pragma unroll
        for (int r = 0; r < 4; r++) {
#pragma unroll
            for (int d = 0; d < 4; d++) pr[r][d] = (ee[r] + d) < tt[r];
            ee[r] += 4;
#pragma unroll
            for (int d = 0; d < 4; d++) {
                int ce = ee[r] + d;
                if (ce >= tt[r]) ce = tt[r] - 1;
                if (ce < 0) ce = 0;
                idx[r][d] = RFL(csr[ce]);
            }
        }
        // accumulate (uniform branches)
#pragma unroll
        for (int r = 0; r < 4; r++)
#pragma unroll
            for (int d = 0; d < 4; d++)
                if (pr[r][d]) {
                    union { unsigned u; float f; } lo0, hi0, lo1, hi1;
                    lo0.u = val[r][d].x << 16; hi0.u = val[r][d].x & 0xffff0000u;
                    lo1.u = val[r][d].y << 16; hi1.u = val[r][d].y & 0xffff0000u;
                    acc[r][0].x += lo0.f; acc[r][0].y += hi0.f;
                    acc[r][1].x += lo1.f; acc[r][1].y += hi1.f;
                }
    }

    // write aggregated rows to LDS (bf16, swizzled)
#pragma unroll
    for (int r = 0; r < 4; r++) {
        int li = wid * 4 + r;
        unsigned px = (unsigned)f2b(acc[r][0].x) | ((unsigned)f2b(acc[r][0].y) << 16);
        unsigned py = (unsigned)f2b(acc[r][1].x) | ((unsigned)f2b(acc[r][1].y) << 16);
        *(uint2*)(ldsb + li * 512 + (laneByte ^ ((li & 7) << 4))) = make_uint2(px, py);
    }
    __syncthreads();

    // ---- phase 2: A fragments ----
    const int m = lane & 15;
    const int g = lane >> 4;
    bf16x8 a[8];
#pragma unroll
    for (int ks = 0; ks < 8; ks++) {
        int boff = (g * 16 + ks * 64) ^ ((m & 7) << 4);
        a[ks] = *(const bf16x8*)(ldsb + m * 512 + boff);
    }
    __syncthreads();

    // ---- phase 3: MFMA, wave owns col-tiles wid*4..wid*4+3 ----
    f32x4 acc2[4];
#pragma unroll
    for (int t = 0; t < 4; t++) acc2[t] = (f32x4){0.f, 0.f, 0.f, 0.f};
    const bf16x8* wp = (const bf16x8*)Wsw + lane;
#pragma unroll
    for (int t = 0; t < 4; t++) {
        int nt = wid * 4 + t;
        bf16x8 b[8];
#pragma unroll
        for (int ks = 0; ks < 8; ks++) b[ks] = wp[(nt * 8 + ks) * 64];
#pragma unroll
        for (int ks = 0; ks < 8; ks++)
            acc2[t] = __builtin_amdgcn_mfma_f32_16x16x32_bf16(a[ks], b[ks], acc2[t], 0, 0, 0);
    }

    // ---- phase 4: C -> LDS (bf16, swizzled) ----
#pragma unroll
    for (int t = 0; t < 4; t++) {
        int col = (wid * 4 + t) * 16 + m;
#pragma unroll
        for (int r = 0; r < 4; r++) {
            int row = g * 4 + r;
            *(u16*)(ldsb + row * 512 + ((col * 2) ^ ((row & 7) << 4))) = f2b(acc2[t][r]);
        }
    }
    __syncthreads();

    // ---- phase 5: epilogue relu + bias + residual ----
    {
        int row = threadIdx.x >> 4;
        int cb0 = (threadIdx.x & 15) * 16;
#pragma unroll
        for (int p = 0; p < 2; p++) {
            int cb = cb0 + p * 256;
            ushort8 c = *(const ushort8*)(ldsb + row * 512 + (cb ^ ((row & 7) << 4)));
            int gcol = cb >> 1;
            size_t gidx = (size_t)(row0 + row) * EMB + gcol;
            ushort8 hres = *(const ushort8*)&Hin[gidx];
            float4 bq0 = *(const float4*)&bias[gcol];
            float4 bq1 = *(const float4*)&bias[gcol + 4];
            float bb[8] = {bq0.x, bq0.y, bq0.z, bq0.w, bq1.x, bq1.y, bq1.z, bq1.w};
            ushort8 o;
#pragma unroll
            for (int j = 0; j < 8; j++)
                o[j] = f2b(fmaxf(b2f(c[j]) + bb[j], 0.f) + b2f(hres[j]));
            *(ushort8*)&Hout[gidx] = o;
        }
    }
}

// ---------------- pooling + head (fused) ----------------

__global__ void graph_bounds(const int* __restrict__ seg, int* __restrict__ gs, int n, int B) {
    int i = blockIdx.x * 256 + threadIdx.x;
    if (i >= n) return;
    int c = seg[i];
    int p = (i == 0) ? -1 : seg[i - 1];
    for (int b = p + 1; b <= c; b++) gs[b] = i;
    if (i == n - 1) {
        for (int b = c + 1; b <= B; b++) gs[b] = n;
    }
}

__global__ __launch_bounds__(256) void pool_head(const u16* __restrict__ h, const int* __restrict__ gs,
                                                 const float* __restrict__ Wp1, const float* __restrict__ Wp2,
                                                 const float* __restrict__ bp2, float* __restrict__ out) {
    __shared__ float gpq[4][EMB];
    __shared__ float gp[EMB];
    __shared__ float red[HID];
    int b = blockIdx.x, t = threadIdx.x;
    int s = gs[b], e = gs[b + 1];
    int q = t >> 6, ch4 = (t & 63) * 4;
    float a0 = 0.f, a1 = 0.f, a2 = 0.f, a3 = 0.f;
    int r = s + q;
    for (; r + 4 < e; r += 8) {
        ushort4 va = *(const ushort4*)&h[(size_t)r * EMB + ch4];
        ushort4 vb = *(const ushort4*)&h[(size_t)(r + 4) * EMB + ch4];
        a0 += b2f(va.x) + b2f(vb.x);
        a1 += b2f(va.y) + b2f(vb.y);
        a2 += b2f(va.z) + b2f(vb.z);
        a3 += b2f(va.w) + b2f(vb.w);
    }
    if (r < e) {
        ushort4 va = *(const ushort4*)&h[(size_t)r * EMB + ch4];
        a0 += b2f(va.x); a1 += b2f(va.y); a2 += b2f(va.z); a3 += b2f(va.w);
    }
    *(float4*)&gpq[q][ch4] = make_float4(a0, a1, a2, a3);
    __syncthreads();
    gp[t] = gpq[0][t] + gpq[1][t] + gpq[2][t] + gpq[3][t];
    __syncthreads();
    if (t < HID) {
        float acc = 0.f;
        const float4* wr = (const float4*)&Wp1[(size_t)t * EMB];
        const float4* gp4 = (const float4*)gp;
#pragma unroll 8
        for (int k = 0; k < EMB / 4; k++) {
            float4 w = wr[k], gg = gp4[k];
            acc += w.x * gg.x + w.y * gg.y + w.z * gg.z + w.w * gg.w;
        }
        red[t] = fmaxf(acc, 0.f) * Wp2[t];
    }
    __syncthreads();
    for (int off = 64; off > 0; off >>= 1) {
        if (t < off) red[t] += red[t + off];
        __syncthreads();
    }
    if (t == 0) out[b] = red[0] + bp2[0];
}

// ---------------- launch ----------------

extern "C" void kernel_launch(void* const* d_in, const int* in_sizes, int n_in,
                              void* d_out, int out_size, void* d_ws, size_t ws_size,
                              hipStream_t stream) {
    const float* x    = (const float*)d_in[0];
    const int*   src  = (const int*)d_in[1];
    const int*   dst  = (const int*)d_in[2];
    const int*   seg  = (const int*)d_in[3];
    const float* W_emb= (const float*)d_in[4];
    const float* W1   = (const float*)d_in[5];
    const float* b1   = (const float*)d_in[6];
    const float* W2   = (const float*)d_in[7];
    const float* b2   = (const float*)d_in[8];
    const float* W3   = (const float*)d_in[9];
    const float* b3   = (const float*)d_in[10];
    const float* Wp1  = (const float*)d_in[11];
    const float* Wp2  = (const float*)d_in[12];
    const float* bp2  = (const float*)d_in[13];
    float* out = (float*)d_out;

    char* ws = (char*)d_ws;
    size_t off = 0;
    auto alloc = [&](size_t bytes) -> void* {
        void* p = ws + off;
        off = (off + bytes + 255) & ~(size_t)255;
        return p;
    };
    const int N = N_NODES, E = N_EDGES, G = N_GRAPHS;
    u16* hA     = (u16*)alloc((size_t)N * EMB * 2);
    u16* hB     = (u16*)alloc((size_t)N * EMB * 2);
    u16* h0     = (u16*)alloc((size_t)N * IN_CH * 2);
    u16* Wsw1   = (u16*)alloc(16 * 64 * 8 * 2);
    u16* Wsw2   = (u16*)alloc(256 * 256 * 2);
    u16* Wsw3   = (u16*)alloc(256 * 256 * 2);
    int* rowptr = (int*)alloc((size_t)(N + 1) * 4);
    int* deg    = (int*)alloc((size_t)N * 4);
    int* csr    = (int*)alloc((size_t)E * 4);
    int* partials = (int*)alloc(1024 * 4);
    int* gs     = (int*)alloc((size_t)(G + 1) * 4);

    if (off > ws_size) return;  // clean failure instead of OOB crash

    // CSR build (by dst)
    hipMemsetAsync(deg, 0, (size_t)N * 4, stream);
    count_deg<<<E / 256, 256, 0, stream>>>(dst, deg, E);
    scan_a<<<196, 256, 0, stream>>>(deg, rowptr + 1, partials, N);
    scan_b<<<1, 256, 0, stream>>>(partials, 196);
    scan_c<<<782, 256, 0, stream>>>(rowptr, partials, N);
    hipMemsetAsync(deg, 0, (size_t)N * 4, stream);  // reuse as cursor
    fill_csr<<<E / 256, 256, 0, stream>>>(src, dst, rowptr, deg, csr, E);

    // weight packing
    swizzle_w1<<<4, 256, 0, stream>>>(W1, Wsw1);
    swizzle_w<<<32, 256, 0, stream>>>(W2, Wsw2);
    swizzle_w<<<32, 256, 0, stream>>>(W3, Wsw3);

    // layer 1: h0 = bf16(x @ We.T); hA = relu(agg(h0) @ W1.T + b1)
    emb8<<<782, 256, 0, stream>>>(x, W_emb, h0, N);
    fused_l1<<<N / 16, 256, 0, stream>>>(h0, rowptr, csr, Wsw1, b1, hA);

    // layer 2: hB = relu(agg(hA) @ W2.T + b2) + hA
    fused_gcn<<<N / 16, 256, 0, stream>>>(hA, rowptr, csr, Wsw2, b2, hB);
    // layer 3: hA = relu(agg(hB) @ W3.T + b3) + hB
    fused_gcn<<<N / 16, 256, 0, stream>>>(hB, rowptr, csr, Wsw3, b3, hA);

    // pooling + head
    graph_bounds<<<782, 256, 0, stream>>>(seg, gs, N, G);
    pool_head<<<G, 256, 0, stream>>>(hA, gs, Wp1, Wp2, bp2, out);
}

// Round 9
// 445.963 us; speedup vs baseline: 2.5534x; 1.0304x over previous
//
#include <hip/hip_runtime.h>
#include <hip/hip_bf16.h>

#define N_NODES 200000
#define N_EDGES 800000
#define N_GRAPHS 4000
#define D_N 35
#define IN_CH 8
#define EMB 256
#define HID 128

typedef unsigned short u16;
typedef __attribute__((ext_vector_type(8))) short bf16x8;
typedef __attribute__((ext_vector_type(8))) unsigned short ushort8;
typedef __attribute__((ext_vector_type(4))) float f32x4;

__device__ __forceinline__ float b2f(u16 u) {
    union { float f; unsigned v; } x; x.v = ((unsigned)u) << 16; return x.f;
}
__device__ __forceinline__ u16 f2b(float f) {
    union { float f; unsigned v; } x; x.f = f;
    unsigned r = x.v + 0x7fff + ((x.v >> 16) & 1);  // round-nearest-even
    return (u16)(r >> 16);
}
#define RFL(v) __builtin_amdgcn_readfirstlane(v)

// ---------------- CSR build ----------------

__global__ void count_deg(const int* __restrict__ dst, int* __restrict__ deg, int n) {
    int e = blockIdx.x * 256 + threadIdx.x;
    if (e < n) atomicAdd(&deg[dst[e]], 1);
}

__global__ __launch_bounds__(256) void scan_a(const int* __restrict__ deg, int* __restrict__ incl1,
                                              int* __restrict__ partials, int n) {
    __shared__ int s[256];
    int tid = threadIdx.x;
    int base = blockIdx.x * 1024;
    int v[4]; int sum = 0;
#pragma unroll
    for (int j = 0; j < 4; j++) {
        int idx = base + tid * 4 + j;
        v[j] = (idx < n) ? deg[idx] : 0;
        sum += v[j];
    }
    s[tid] = sum; __syncthreads();
    for (int off = 1; off < 256; off <<= 1) {
        int t = (tid >= off) ? s[tid - off] : 0;
        __syncthreads();
        s[tid] += t;
        __syncthreads();
    }
    int run = s[tid] - sum;
#pragma unroll
    for (int j = 0; j < 4; j++) {
        int idx = base + tid * 4 + j;
        run += v[j];
        if (idx < n) incl1[idx] = run;
    }
    if (tid == 255) partials[blockIdx.x] = s[255];
}

__global__ __launch_bounds__(256) void scan_b(int* __restrict__ partials, int np) {
    __shared__ int s[256];
    int tid = threadIdx.x;
    int v = (tid < np) ? partials[tid] : 0;
    s[tid] = v; __syncthreads();
    for (int off = 1; off < 256; off <<= 1) {
        int t = (tid >= off) ? s[tid - off] : 0;
        __syncthreads();
        s[tid] += t;
        __syncthreads();
    }
    if (tid < np) partials[tid] = s[tid] - v;
}

__global__ void scan_c(int* __restrict__ rowptr, const int* __restrict__ partials, int n) {
    int i = blockIdx.x * 256 + threadIdx.x;
    if (i < n) rowptr[1 + i] += partials[i >> 10];
    if (i == 0) rowptr[0] = 0;
}

// slot-allocate by atomicSub on counts (cnt ends at 0; intra-row order nondeterministic, sum unchanged)
__global__ void fill_csr(const int* __restrict__ src, const int* __restrict__ dst,
                         const int* __restrict__ rowptr, int* __restrict__ cnt,
                         int* __restrict__ csr, int n) {
    int e = blockIdx.x * 256 + threadIdx.x;
    if (e >= n) return;
    int d = dst[e];
    int p = atomicSub(&cnt[d], 1) - 1;
    csr[rowptr[d] + p] = src[e];
}

// ---------------- weight packing ----------------

// W2/W3 [256 out][256 in] fp32 -> MFMA B-fragment order bf16 (one launch for both)
__global__ __launch_bounds__(256) void swizzle_w23(const float* __restrict__ W2, const float* __restrict__ W3,
                                                   u16* __restrict__ Wsw2, u16* __restrict__ Wsw3) {
    int t = blockIdx.x * 256 + threadIdx.x;  // 16384 threads
    const float* W = (t < 8192) ? W2 : W3;
    u16* Wsw = (t < 8192) ? Wsw2 : Wsw3;
    int tl = t & 8191;
    int lane = tl & 63;
    int n = ((tl >> 9) << 4) + (lane & 15);
    int k0 = (((tl >> 6) & 7) << 5) + ((lane >> 4) << 3);
    u16 v[8];
#pragma unroll
    for (int j = 0; j < 8; j++) v[j] = f2b(W[(size_t)n * 256 + k0 + j]);
    ushort4* o = (ushort4*)&Wsw[(size_t)tl * 8];
    o[0] = make_ushort4(v[0], v[1], v[2], v[3]);
    o[1] = make_ushort4(v[4], v[5], v[6], v[7]);
}

// W1 [256 out][8 in] -> B-fragment order for one 16x16x32 MFMA (k 8..31 zero)
__global__ __launch_bounds__(256) void swizzle_w1(const float* __restrict__ W1, u16* __restrict__ Wsw) {
    int t = blockIdx.x * 256 + threadIdx.x;  // 1024 threads: nt(16) x lane(64)
    int lane = t & 63;
    int nt = t >> 6;
    int n = nt * 16 + (lane & 15);
    int g = lane >> 4;
    u16 v[8];
#pragma unroll
    for (int j = 0; j < 8; j++) v[j] = (g == 0) ? f2b(W1[n * 8 + j]) : (u16)0;
    ushort4* o = (ushort4*)&Wsw[(size_t)t * 8];
    o[0] = make_ushort4(v[0], v[1], v[2], v[3]);
    o[1] = make_ushort4(v[4], v[5], v[6], v[7]);
}

// ---------------- emb: h0 = bf16(x @ We.T)  [N,8] ----------------
__global__ __launch_bounds__(256) void emb8(const float* __restrict__ x, const float* __restrict__ We,
                                            u16* __restrict__ h0, int n) {
    __shared__ float ws[IN_CH * D_N];
    int tid = threadIdx.x;
    for (int i = tid; i < IN_CH * D_N; i += 256) ws[i] = We[i];
    __syncthreads();
    int node = blockIdx.x * 256 + tid;
    if (node >= n) return;
    float xr[D_N];
    const float* xp = &x[(size_t)node * D_N];
#pragma unroll
    for (int k = 0; k < D_N; k++) xr[k] = xp[k];
    ushort8 o;
#pragma unroll
    for (int j = 0; j < IN_CH; j++) {
        float acc = 0.f;
#pragma unroll
        for (int k = 0; k < D_N; k++) acc += xr[k] * ws[j * D_N + k];
        o[j] = f2b(acc);
    }
    *(ushort8*)&h0[(size_t)node * IN_CH] = o;
}

// ---------------- fused layer 1: agg8 + MFMA GEMM (8->256) ----------------
__global__ __launch_bounds__(256) void fused_l1(const u16* __restrict__ h0,
                                                const int* __restrict__ rowptr,
                                                const int* __restrict__ csr,
                                                const u16* __restrict__ Wsw1,
                                                const float* __restrict__ bias,
                                                u16* __restrict__ Hout) {
    __shared__ __attribute__((aligned(16))) u16 lds[16][256];  // 8 KB; agg uses [16][8] front
    const int wid = threadIdx.x >> 6;
    const int lane = threadIdx.x & 63;
    const int row0 = blockIdx.x * 16;
    char* ldsb = (char*)lds;
    const char* h0c = (const char*)h0;

    // ---- phase 1: each wave aggregates rows rbase..rbase+3 (16 edges/iter/row) ----
    const int slot = lane >> 2;          // edge slot 0..15
    const int cid2 = (lane & 3) * 4;     // byte offset of this lane's 2 channels
    const int rbase = row0 + wid * 4;
    int s0 = RFL(rowptr[rbase + 0]);
    int s1 = RFL(rowptr[rbase + 1]);
    int s2 = RFL(rowptr[rbase + 2]);
    int s3 = RFL(rowptr[rbase + 3]);
    int s4 = RFL(rowptr[rbase + 4]);
    int es[5] = {s0, s1, s2, s3, s4};
#pragma unroll
    for (int r = 0; r < 4; r++) {
        int er = es[r], tr = es[r + 1];
        float2 acc = make_float2(0.f, 0.f);
        for (int eb = er; eb < tr; eb += 16) {
            int e = eb + slot;
            int ce = e < tr ? e : tr - 1;
            int sidx = csr[ce];
            unsigned v = *(const unsigned*)(h0c + (size_t)sidx * 16 + cid2);
            if (e < tr) {
                union { unsigned u; float f; } lo, hi;
                lo.u = v << 16; hi.u = v & 0xffff0000u;
                acc.x += lo.f; acc.y += hi.f;
            }
        }
        acc.x += __shfl_xor(acc.x, 4, 64);  acc.y += __shfl_xor(acc.y, 4, 64);
        acc.x += __shfl_xor(acc.x, 8, 64);  acc.y += __shfl_xor(acc.y, 8, 64);
        acc.x += __shfl_xor(acc.x, 16, 64); acc.y += __shfl_xor(acc.y, 16, 64);
        acc.x += __shfl_xor(acc.x, 32, 64); acc.y += __shfl_xor(acc.y, 32, 64);
        if (lane < 4) {
            unsigned pk = (unsigned)f2b(acc.x) | ((unsigned)f2b(acc.y) << 16);
            *(unsigned*)(ldsb + (wid * 4 + r) * 16 + cid2) = pk;
        }
    }
    __syncthreads();

    // ---- phase 2: A fragment (K=32: k<8 real, rest zero) ----
    const int m = lane & 15;
    const int g = lane >> 4;
    bf16x8 a = {};
    if (g == 0) a = *(const bf16x8*)(ldsb + m * 16);
    __syncthreads();

    // ---- phase 3: 1 MFMA per col-tile ----
    f32x4 acc[4];
#pragma unroll
    for (int t = 0; t < 4; t++) acc[t] = (f32x4){0.f, 0.f, 0.f, 0.f};
    const bf16x8* wp = (const bf16x8*)Wsw1 + lane;
#pragma unroll
    for (int t = 0; t < 4; t++) {
        bf16x8 b = wp[(wid * 4 + t) * 64];
        acc[t] = __builtin_amdgcn_mfma_f32_16x16x32_bf16(a, b, acc[t], 0, 0, 0);
    }

    // ---- phase 4: C -> LDS (bf16, swizzled [16][512B]) ----
#pragma unroll
    for (int t = 0; t < 4; t++) {
        int col = (wid * 4 + t) * 16 + m;
#pragma unroll
        for (int r = 0; r < 4; r++) {
            int row = g * 4 + r;
            *(u16*)(ldsb + row * 512 + ((col * 2) ^ ((row & 7) << 4))) = f2b(acc[t][r]);
        }
    }
    __syncthreads();

    // ---- phase 5: epilogue relu + bias ----
    {
        int row = threadIdx.x >> 4;
        int cb0 = (threadIdx.x & 15) * 16;
#pragma unroll
        for (int p = 0; p < 2; p++) {
            int cb = cb0 + p * 256;
            ushort8 c = *(const ushort8*)(ldsb + row * 512 + (cb ^ ((row & 7) << 4)));
            int gcol = cb >> 1;
            size_t gidx = (size_t)(row0 + row) * EMB + gcol;
            float4 bq0 = *(const float4*)&bias[gcol];
            float4 bq1 = *(const float4*)&bias[gcol + 4];
            float bb[8] = {bq0.x, bq0.y, bq0.z, bq0.w, bq1.x, bq1.y, bq1.z, bq1.w};
            ushort8 o;
#pragma unroll
            for (int j = 0; j < 8; j++)
                o[j] = f2b(fmaxf(b2f(c[j]) + bb[j], 0.f));
            *(ushort8*)&Hout[gidx] = o;
        }
    }
}

// ---------------- fused GCN layer (2,3) ----------------
// Hout[r,:] = relu( (sum_{e: dst=r} Hin[src_e,:]) @ W.T + bias ) + Hin[r,:]
// Merged edge-stream gather: wave's 4 consecutive rows have contiguous CSR ranges.
// Stream edges [s0,t3) 8-deep; route to acc row by wave-uniform SGPR compares.
__global__ __launch_bounds__(256, 8) void fused_gcn(const u16* __restrict__ Hin,
                                                    const int* __restrict__ rowptr,
                                                    const int* __restrict__ csr,
                                                    const u16* __restrict__ Wsw,
                                                    const float* __restrict__ bias,
                                                    u16* __restrict__ Hout) {
    __shared__ __attribute__((aligned(16))) u16 lds[16][256];  // 8 KB
    const int wid = threadIdx.x >> 6;
    const int lane = threadIdx.x & 63;
    const int row0 = blockIdx.x * 16;
    char* ldsb = (char*)lds;
    const char* hbase = (const char*)Hin;
    const int laneByte = lane * 8;

    // ---- phase 1: merged-stream gather (all control in SGPRs) ----
    const int rbase = row0 + wid * 4;
    int s0 = RFL(rowptr[rbase + 0]);
    int t0 = RFL(rowptr[rbase + 1]);
    int t1 = RFL(rowptr[rbase + 2]);
    int t2 = RFL(rowptr[rbase + 3]);
    int t3 = RFL(rowptr[rbase + 4]);

    float4 ar0 = make_float4(0.f, 0.f, 0.f, 0.f);
    float4 ar1 = ar0, ar2 = ar0, ar3 = ar0;

    int idx[8];
#pragma unroll
    for (int d = 0; d < 8; d++) {
        int ce = s0 + d;
        if (ce > t3 - 1) ce = t3 - 1;
        if (ce < 0) ce = 0;
        idx[d] = RFL(csr[ce]);
    }
    int ee = s0;
    while (ee < t3) {
        uint2 v[8];
#pragma unroll
        for (int d = 0; d < 8; d++)
            v[d] = *(const uint2*)(hbase + (size_t)idx[d] * (EMB * 2) + laneByte);
        int eb = ee;
        ee += 8;
#pragma unroll
        for (int d = 0; d < 8; d++) {
            int ce = ee + d;
            if (ce > t3 - 1) ce = t3 - 1;
            if (ce < 0) ce = 0;
            idx[d] = RFL(csr[ce]);
        }
#pragma unroll
        for (int d = 0; d < 8; d++) {
            int ed = eb + d;
            if (ed < t3) {  // wave-uniform
                union { unsigned u; float f; } l0, h0, l1, h1;
                l0.u = v[d].x << 16; h0.u = v[d].x & 0xffff0000u;
                l1.u = v[d].y << 16; h1.u = v[d].y & 0xffff0000u;
                if (ed < t0)      { ar0.x += l0.f; ar0.y += h0.f; ar0.z += l1.f; ar0.w += h1.f; }
                else if (ed < t1) { ar1.x += l0.f; ar1.y += h0.f; ar1.z += l1.f; ar1.w += h1.f; }
                else if (ed < t2) { ar2.x += l0.f; ar2.y += h0.f; ar2.z += l1.f; ar2.w += h1.f; }
                else              { ar3.x += l0.f; ar3.y += h0.f; ar3.z += l1.f; ar3.w += h1.f; }
            }
        }
    }

    // write aggregated rows to LDS (bf16, swizzled)
    {
        float4 ars[4] = {ar0, ar1, ar2, ar3};
#pragma unroll
        for (int r = 0; r < 4; r++) {
            int li = wid * 4 + r;
            unsigned px = (unsigned)f2b(ars[r].x) | ((unsigned)f2b(ars[r].y) << 16);
            unsigned py = (unsigned)f2b(ars[r].z) | ((unsigned)f2b(ars[r].w) << 16);
            *(uint2*)(ldsb + li * 512 + (laneByte ^ ((li & 7) << 4))) = make_uint2(px, py);
        }
    }
    __syncthreads();

    // ---- phase 2: A fragments ----
    const int m = lane & 15;
    const int g = lane >> 4;
    bf16x8 a[8];
#pragma unroll
    for (int ks = 0; ks < 8; ks++) {
        int boff = (g * 16 + ks * 64) ^ ((m & 7) << 4);
        a[ks] = *(const bf16x8*)(ldsb + m * 512 + boff);
    }
    __syncthreads();

    // ---- phase 3: MFMA, wave owns col-tiles wid*4..wid*4+3 ----
    f32x4 acc2[4];
#pragma unroll
    for (int t = 0; t < 4; t++) acc2[t] = (f32x4){0.f, 0.f, 0.f, 0.f};
    const bf16x8* wp = (const bf16x8*)Wsw + lane;
#pragma unroll
    for (int t = 0; t < 4; t++) {
        int nt = wid * 4 + t;
        bf16x8 b[8];
#pragma unroll
        for (int ks = 0; ks < 8; ks++) b[ks] = wp[(nt * 8 + ks) * 64];
#pragma unroll
        for (int ks = 0; ks < 8; ks++)
            acc2[t] = __builtin_amdgcn_mfma_f32_16x16x32_bf16(a[ks], b[ks], acc2[t], 0, 0, 0);
    }

    // ---- phase 4: C -> LDS (bf16, swizzled) ----
#pragma unroll
    for (int t = 0; t < 4; t++) {
        int col = (wid * 4 + t) * 16 + m;
#pragma unroll
        for (int r = 0; r < 4; r++) {
            int row = g * 4 + r;
            *(u16*)(ldsb + row * 512 + ((col * 2) ^ ((row & 7) << 4))) = f2b(acc2[t][r]);
        }
    }
    __syncthreads();

    // ---- phase 5: epilogue relu + bias + residual ----
    {
        int row = threadIdx.x >> 4;
        int cb0 = (threadIdx.x & 15) * 16;
#pragma unroll
        for (int p = 0; p < 2; p++) {
            int cb = cb0 + p * 256;
            ushort8 c = *(const ushort8*)(ldsb + row * 512 + (cb ^ ((row & 7) << 4)));
            int gcol = cb >> 1;
            size_t gidx = (size_t)(row0 + row) * EMB + gcol;
            ushort8 hres = *(const ushort8*)&Hin[gidx];
            float4 bq0 = *(const float4*)&bias[gcol];
            float4 bq1 = *(const float4*)&bias[gcol + 4];
            float bb[8] = {bq0.x, bq0.y, bq0.z, bq0.w, bq1.x, bq1.y, bq1.z, bq1.w};
            ushort8 o;
#pragma unroll
            for (int j = 0; j < 8; j++)
                o[j] = f2b(fmaxf(b2f(c[j]) + bb[j], 0.f) + b2f(hres[j]));
            *(ushort8*)&Hout[gidx] = o;
        }
    }
}

// ---------------- pooling + head (fused) ----------------

__global__ void graph_bounds(const int* __restrict__ seg, int* __restrict__ gs, int n, int B) {
    int i = blockIdx.x * 256 + threadIdx.x;
    if (i >= n) return;
    int c = seg[i];
    int p = (i == 0) ? -1 : seg[i - 1];
    for (int b = p + 1; b <= c; b++) gs[b] = i;
    if (i == n - 1) {
        for (int b = c + 1; b <= B; b++) gs[b] = n;
    }
}

__global__ __launch_bounds__(256) void pool_head(const u16* __restrict__ h, const int* __restrict__ gs,
                                                 const float* __restrict__ Wp1, const float* __restrict__ Wp2,
                                                 const float* __restrict__ bp2, float* __restrict__ out) {
    __shared__ float gpq[4][EMB];
    __shared__ float gp[EMB];
    __shared__ float red[HID];
    int b = blockIdx.x, t = threadIdx.x;
    int s = gs[b], e = gs[b + 1];
    int q = t >> 6, ch4 = (t & 63) * 4;
    float a0 = 0.f, a1 = 0.f, a2 = 0.f, a3 = 0.f;
    int r = s + q;
    for (; r + 4 < e; r += 8) {
        ushort4 va = *(const ushort4*)&h[(size_t)r * EMB + ch4];
        ushort4 vb = *(const ushort4*)&h[(size_t)(r + 4) * EMB + ch4];
        a0 += b2f(va.x) + b2f(vb.x);
        a1 += b2f(va.y) + b2f(vb.y);
        a2 += b2f(va.z) + b2f(vb.z);
        a3 += b2f(va.w) + b2f(vb.w);
    }
    if (r < e) {
        ushort4 va = *(const ushort4*)&h[(size_t)r * EMB + ch4];
        a0 += b2f(va.x); a1 += b2f(va.y); a2 += b2f(va.z); a3 += b2f(va.w);
    }
    *(float4*)&gpq[q][ch4] = make_float4(a0, a1, a2, a3);
    __syncthreads();
    gp[t] = gpq[0][t] + gpq[1][t] + gpq[2][t] + gpq[3][t];
    __syncthreads();
    if (t < HID) {
        float acc = 0.f;
        const float4* wr = (const float4*)&Wp1[(size_t)t * EMB];
        const float4* gp4 = (const float4*)gp;
#pragma unroll 8
        for (int k = 0; k < EMB / 4; k++) {
            float4 w = wr[k], gg = gp4[k];
            acc += w.x * gg.x + w.y * gg.y + w.z * gg.z + w.w * gg.w;
        }
        red[t] = fmaxf(acc, 0.f) * Wp2[t];
    }
    __syncthreads();
    for (int off = 64; off > 0; off >>= 1) {
        if (t < off) red[t] += red[t + off];
        __syncthreads();
    }
    if (t == 0) out[b] = red[0] + bp2[0];
}

// ---------------- launch ----------------

extern "C" void kernel_launch(void* const* d_in, const int* in_sizes, int n_in,
                              void* d_out, int out_size, void* d_ws, size_t ws_size,
                              hipStream_t stream) {
    const float* x    = (const float*)d_in[0];
    const int*   src  = (const int*)d_in[1];
    const int*   dst  = (const int*)d_in[2];
    const int*   seg  = (const int*)d_in[3];
    const float* W_emb= (const float*)d_in[4];
    const float* W1   = (const float*)d_in[5];
    const float* b1   = (const float*)d_in[6];
    const float* W2   = (const float*)d_in[7];
    const float* b2   = (const float*)d_in[8];
    const float* W3   = (const float*)d_in[9];
    const float* b3   = (const float*)d_in[10];
    const float* Wp1  = (const float*)d_in[11];
    const float* Wp2  = (const float*)d_in[12];
    const float* bp2  = (const float*)d_in[13];
    float* out = (float*)d_out;

    char* ws = (char*)d_ws;
    size_t off = 0;
    auto alloc = [&](size_t bytes) -> void* {
        void* p = ws + off;
        off = (off + bytes + 255) & ~(size_t)255;
        return p;
    };
    const int N = N_NODES, E = N_EDGES, G = N_GRAPHS;
    u16* hA     = (u16*)alloc((size_t)N * EMB * 2);
    u16* hB     = (u16*)alloc((size_t)N * EMB * 2);
    u16* h0     = (u16*)alloc((size_t)N * IN_CH * 2);
    u16* Wsw1   = (u16*)alloc(16 * 64 * 8 * 2);
    u16* Wsw2   = (u16*)alloc(256 * 256 * 2);
    u16* Wsw3   = (u16*)alloc(256 * 256 * 2);
    int* rowptr = (int*)alloc((size_t)(N + 1) * 4);
    int* deg    = (int*)alloc((size_t)N * 4);
    int* csr    = (int*)alloc((size_t)E * 4);
    int* partials = (int*)alloc(1024 * 4);
    int* gs     = (int*)alloc((size_t)(G + 1) * 4);

    if (off > ws_size) return;  // clean failure instead of OOB crash

    // CSR build (by dst); fill_csr consumes deg counts via atomicSub (no cursor/memset #2)
    hipMemsetAsync(deg, 0, (size_t)N * 4, stream);
    count_deg<<<E / 256, 256, 0, stream>>>(dst, deg, E);
    scan_a<<<196, 256, 0, stream>>>(deg, rowptr + 1, partials, N);
    scan_b<<<1, 256, 0, stream>>>(partials, 196);
    scan_c<<<782, 256, 0, stream>>>(rowptr, partials, N);
    fill_csr<<<E / 256, 256, 0, stream>>>(src, dst, rowptr, deg, csr, E);

    // weight packing
    swizzle_w1<<<4, 256, 0, stream>>>(W1, Wsw1);
    swizzle_w23<<<64, 256, 0, stream>>>(W2, W3, Wsw2, Wsw3);

    // layer 1: h0 = bf16(x @ We.T); hA = relu(agg(h0) @ W1.T + b1)
    emb8<<<782, 256, 0, stream>>>(x, W_emb, h0, N);
    fused_l1<<<N / 16, 256, 0, stream>>>(h0, rowptr, csr, Wsw1, b1, hA);

    // layer 2: hB = relu(agg(hA) @ W2.T + b2) + hA
    fused_gcn<<<N / 16, 256, 0, stream>>>(hA, rowptr, csr, Wsw2, b2, hB);
    // layer 3: hA = relu(agg(hB) @ W3.T + b3) + hB
    fused_gcn<<<N / 16, 256, 0, stream>>>(hB, rowptr, csr, Wsw3, b3, hA);

    // pooling + head
    graph_bounds<<<782, 256, 0, stream>>>(seg, gs, N, G);
    pool_head<<<G, 256, 0, stream>>>(hA, gs, Wp1, Wp2, bp2, out);
}